// Round 2
// baseline (314.356 us; speedup 1.0000x reference)
//
#include <hip/hip_runtime.h>

typedef __bf16 bf16;
typedef bf16 bf16x8 __attribute__((ext_vector_type(8)));
typedef bf16 bf16x4 __attribute__((ext_vector_type(4)));
typedef float f32x4 __attribute__((ext_vector_type(4)));

#define B_ 4
#define N1 4096
#define N2 256
#define DIM 1024
#define HEADS 16
#define DH 64
#define INNER 1024
#define ASPLIT 4
#define KEYS_PER_SPLIT (N1 / ASPLIT)      // 1024
#define SPLIT_ELEMS (4 * 16 * 256 * 64)   // elems per split partial (bf16)
#define ROWS_TOTAL (4 * HEADS * N2)       // 16384 rows per split

// async global->LDS, 16B per lane; LDS dest = wave-uniform base + lane*16
typedef __attribute__((address_space(1))) const void gvoid_t;
typedef __attribute__((address_space(3))) void lvoid_t;
__device__ __forceinline__ void async16(const void* g, void* l) {
  __builtin_amdgcn_global_load_lds((gvoid_t*)g, (lvoid_t*)l, 16, 0, 0);
}

// ---------------------------------------------------------------------------
// prep: fused weight transposes + both LayerNorms in one launch. (unchanged)
// ---------------------------------------------------------------------------
__global__ __launch_bounds__(256) void prep(
    const float* __restrict__ Wq, const float* __restrict__ Wkv,
    const float* __restrict__ Wout, bf16* __restrict__ WqT,
    bf16* __restrict__ WkvT, bf16* __restrict__ WoutT,
    const float* __restrict__ x, const float* __restrict__ latents,
    const float* __restrict__ ln1w, const float* __restrict__ ln1b,
    const float* __restrict__ ln2w, const float* __restrict__ ln2b,
    bf16* __restrict__ xn, bf16* __restrict__ lnl) {
  __shared__ float tile[32][33];
  int t = blockIdx.x;
  if (t < 4096) {  // ---- transpose path ----
    const float* src;
    bf16* dst;
    int N;
    if (t < 1024) { src = Wq; dst = WqT; N = 1024; }
    else if (t < 3072) { t -= 1024; src = Wkv; dst = WkvT; N = 2048; }
    else { t -= 3072; src = Wout; dst = WoutT; N = 1024; }
    int ntiles = N >> 5;
    int n0 = (t % ntiles) * 32, k0 = (t / ntiles) * 32;
    int xx = threadIdx.x & 31, yy = threadIdx.x >> 5;
    for (int j = 0; j < 4; j++)
      tile[yy + 8 * j][xx] = src[(size_t)(k0 + yy + 8 * j) * N + n0 + xx];
    __syncthreads();
    for (int j = 0; j < 4; j++)
      dst[(size_t)(n0 + yy + 8 * j) * 1024 + k0 + xx] = (bf16)tile[xx][yy + 8 * j];
    return;
  }
  // ---- LN path ----
  int wv = threadIdx.x >> 6, lane = threadIdx.x & 63;
  int grow = (t - 4096) * 4 + wv;
  const float *src, *w, *bb;
  bf16* dst;
  int row;
  if (grow < 16384) { src = x; w = ln1w; bb = ln1b; dst = xn; row = grow; }
  else { src = latents; w = ln2w; bb = ln2b; dst = lnl; row = grow - 16384; }
  const float4* p = (const float4*)(src + (size_t)row * DIM);
  float4 v[4];
  for (int j = 0; j < 4; j++) v[j] = p[j * 64 + lane];
  float s = 0.f, sq = 0.f;
  for (int j = 0; j < 4; j++) {
    s += v[j].x + v[j].y + v[j].z + v[j].w;
    sq += v[j].x * v[j].x + v[j].y * v[j].y + v[j].z * v[j].z + v[j].w * v[j].w;
  }
  for (int off = 32; off; off >>= 1) {
    s += __shfl_xor(s, off, 64);
    sq += __shfl_xor(sq, off, 64);
  }
  float mu = s * (1.0f / DIM);
  float var = sq * (1.0f / DIM) - mu * mu;
  float r = rsqrtf(var + 1e-5f);
  for (int j = 0; j < 4; j++) {
    float4 wv4 = ((const float4*)w)[j * 64 + lane];
    float4 bv4 = ((const float4*)bb)[j * 64 + lane];
    bf16x4 o;
    o[0] = (bf16)((v[j].x - mu) * r * wv4.x + bv4.x);
    o[1] = (bf16)((v[j].y - mu) * r * wv4.y + bv4.y);
    o[2] = (bf16)((v[j].z - mu) * r * wv4.z + bv4.z);
    o[3] = (bf16)((v[j].w - mu) * r * wv4.w + bv4.w);
    *(bf16x4*)(dst + (size_t)row * DIM + (j * 64 + lane) * 4) = o;
  }
}

// ---------------------------------------------------------------------------
// Big GEMM (kv): 256x256 tiles, BK=64, paired-tile persistent blocks.
// 256 blocks, each computes (mt,nt) then (mt+32,nt): same B panel (L2-hot
// restage), 32-deep K-loop, mid-stream acc flush with DIRECT stores (no LDS
// touch -> pipeline never drains between the two tiles).
// 6 barriers per K-tile: post-MFMA barriers kept only where a WAR hazard
// exists (post-P2: P3's stage overwrites A0 read in P1/P2; tile end).
// Dropping the post-P1/post-P3 barriers lets fast waves issue next-phase
// ds_reads while slow waves MFMA -> LDS backlog overlaps the MFMA window.
// One counted s_waitcnt vmcnt(4) per K-tile; never drains to 0 in the loop.
// V-half C-fragments are key-contiguous in the V^T layout -> b64 direct
// stores; the old LDS-transpose epilogue is deleted.
// ---------------------------------------------------------------------------
__device__ __forceinline__ int swz_off(int row, int cb) {
  int line = row >> 1;
  return (line << 7) + (((((row & 1) << 2) | cb) ^ (line & 7)) << 4);
}

#define MFMA_BLOCK(base)                                              \
  _Pragma("unroll") for (int im = 0; im < 4; im++)                    \
      _Pragma("unroll") for (int in = 0; in < 4; in++)                \
          acc[(base) + im][in] = __builtin_amdgcn_mfma_f32_16x16x32_bf16( \
              af[im], bfr[in], acc[(base) + im][in], 0, 0, 0);

__global__ __launch_bounds__(512, 2) void gemm_kv256(
    const bf16* __restrict__ A, const bf16* __restrict__ Bt,
    bf16* __restrict__ Cout, bf16* __restrict__ Cout2) {
  extern __shared__ char smem[];
  int tid = threadIdx.x;
  int lane = tid & 63, wv = tid >> 6;
  int lr = lane & 15, quad = lane >> 4;
  int wr = wv >> 2, wc = wv & 3;
  int bid = blockIdx.x;        // 256 blocks
  int xcd = bid & 7, idx = bid >> 3;  // per-XCD: 4 mt x 8 nt (A 4MB, B 4MB in L2)
  int mt = xcd * 4 + (idx & 3);       // tile1 rows; tile2 = mt+32
  int nt = idx >> 2;                  // 0..7 (same B panel for both tiles)
  int m0 = mt * 256, n0 = nt * 256;

  // fragment byte-offsets within a khalf tile
  int offA[8], offB[4];
#pragma unroll
  for (int im = 0; im < 8; im++) offA[im] = swz_off(wr * 128 + im * 16 + lr, quad);
#pragma unroll
  for (int in = 0; in < 4; in++) offB[in] = swz_off(wc * 64 + in * 16 + lr, quad);

  // staging: unit u = s*512+tid holds logical (row, cb) of the khalf tile
  size_t gA[2], gB[2];
#pragma unroll
  for (int s = 0; s < 2; s++) {
    int u = s * 512 + tid;
    int line = u >> 3, inner = (u & 7) ^ (line & 7);
    int row = line * 2 + (inner >> 2), cb = inner & 3;
    gA[s] = (size_t)(m0 + row) * 1024 + cb * 8;
    gB[s] = (size_t)(n0 + row) * 1024 + cb * 8;
  }
  int ldsS0 = wv * 1024, ldsS1 = 8192 + wv * 1024;  // wave-uniform LDS dests

  // w = logical iteration [0,32) of the staged data; b = target buffer
  auto stA = [&](int b, int kh, int w) {
    char* base = smem + b * 32768 + kh * 16384;
    size_t k0 = (size_t)((w & 15) * 64 + kh * 32) +
                (w >= 16 ? (size_t)8192 * 1024 : 0);  // tile2: rows m0+8192
    async16(&A[gA[0] + k0], base + ldsS0);
    async16(&A[gA[1] + k0], base + ldsS1);
  };
  auto stB = [&](int b, int kh, int w) {
    char* base = smem + 65536 + b * 32768 + kh * 16384;
    size_t k0 = (size_t)((w & 15) * 64 + kh * 32);    // same B panel both tiles
    async16(&Bt[gB[0] + k0], base + ldsS0);
    async16(&Bt[gB[1] + k0], base + ldsS1);
  };

  f32x4 acc[8][4] = {};

  auto storeC = [&](int mbase) {
    if (n0 < 1024) {  // K half: scalar bf16 stores (16-lane 32B segments)
#pragma unroll
      for (int im = 0; im < 8; im++)
#pragma unroll
        for (int in = 0; in < 4; in++) {
          int col = n0 + wc * 64 + in * 16 + lr;
#pragma unroll
          for (int r = 0; r < 4; r++) {
            int row = mbase + wr * 128 + im * 16 + quad * 4 + r;
            Cout[(size_t)row * 1024 + col] = (bf16)acc[im][in][r];
          }
        }
    } else {  // V half: fragment is key-contiguous in V^T -> b64 stores
      int b2 = mbase >> 12;
      int key0 = (mbase & 4095) + wr * 128;
      int c0 = (n0 - 1024) + wc * 64;
#pragma unroll
      for (int im = 0; im < 8; im++)
#pragma unroll
        for (int in = 0; in < 4; in++) {
          bf16x4 pk;
#pragma unroll
          for (int r = 0; r < 4; r++) pk[r] = (bf16)acc[im][in][r];
          *(bf16x4*)&Cout2[((size_t)(b2 * 1024 + c0 + in * 16 + lr)) * 4096 +
                           key0 + im * 16 + quad * 4] = pk;
        }
    }
  };

  // prologue: iter0 kh0+kh1, iter1 kh0; leave iter1-kh0's 4 loads in flight
  stA(0, 0, 0);  stB(0, 0, 0);
  stA(0, 1, 0);  stB(0, 1, 0);
  stA(1, 0, 1);  stB(1, 0, 1);
  asm volatile("s_waitcnt vmcnt(4)" ::: "memory");
  __builtin_amdgcn_s_barrier();

#pragma unroll 1
  for (int u = 0; u < 32; u++) {
    int b = u & 1;
    const char* A0 = smem + b * 32768;
    const char* A1 = A0 + 16384;
    const char* B0 = smem + 65536 + b * 32768;
    const char* B1 = B0 + 16384;
    // clamped tails restage into dead buffer regions -> harmless
    int w1 = (u + 1 < 32) ? u + 1 : 31;
    int w2 = (u + 2 < 32) ? u + 2 : 31;
    bf16x8 af[4], bfr[4];
    // ---- P1: kh0, mh0 ----
#pragma unroll
    for (int in = 0; in < 4; in++) bfr[in] = *(const bf16x8*)(B0 + offB[in]);
#pragma unroll
    for (int im = 0; im < 4; im++) af[im] = *(const bf16x8*)(A0 + offA[im]);
    stA(b ^ 1, 1, w1);
    __builtin_amdgcn_s_barrier();
    __builtin_amdgcn_s_setprio(1);
    MFMA_BLOCK(0)
    __builtin_amdgcn_s_setprio(0);
    // (no barrier: next phase reads stable A0; drift -> LDS/MFMA overlap)
    // ---- P2: kh0, mh1 ----
#pragma unroll
    for (int im = 0; im < 4; im++) af[im] = *(const bf16x8*)(A0 + offA[4 + im]);
    stB(b ^ 1, 1, w1);
    __builtin_amdgcn_s_barrier();
    __builtin_amdgcn_s_setprio(1);
    MFMA_BLOCK(4)
    __builtin_amdgcn_s_setprio(0);
    __builtin_amdgcn_s_barrier();  // WAR: P3's stage overwrites A0 read above
    // ---- P3: kh1, mh0 ----
#pragma unroll
    for (int in = 0; in < 4; in++) bfr[in] = *(const bf16x8*)(B1 + offB[in]);
#pragma unroll
    for (int im = 0; im < 4; im++) af[im] = *(const bf16x8*)(A1 + offA[im]);
    stA(b, 0, w2);
    __builtin_amdgcn_s_barrier();
    __builtin_amdgcn_s_setprio(1);
    MFMA_BLOCK(0)
    __builtin_amdgcn_s_setprio(0);
    // (no barrier: next phase reads stable A1)
    // ---- P4: kh1, mh1 ----
#pragma unroll
    for (int im = 0; im < 4; im++) af[im] = *(const bf16x8*)(A1 + offA[4 + im]);
    stB(b, 0, w2);
    __builtin_amdgcn_s_barrier();
    __builtin_amdgcn_s_setprio(1);
    MFMA_BLOCK(4)
    __builtin_amdgcn_s_setprio(0);
    // counted guard BEFORE the tile-end barrier: all but the newest 4 loads
    // (P3+P4 stages) landed in every wave; barrier publishes cross-wave.
    asm volatile("s_waitcnt vmcnt(4)" ::: "memory");
    __builtin_amdgcn_s_barrier();
    if (u == 15) {  // mid-stream flush of tile1 (no LDS touch, no drain)
      storeC(m0);
#pragma unroll
      for (int im = 0; im < 8; im++)
#pragma unroll
        for (int in = 0; in < 4; in++) acc[im][in] = (f32x4){0.f, 0.f, 0.f, 0.f};
    }
  }
  // final epilogue: direct stores, no LDS reuse -> no drain needed
  storeC(m0 + 8192);
}

// ---------------------------------------------------------------------------
// Small GEMM: 64x64 tile, BK=64. (unchanged)
// ---------------------------------------------------------------------------
template <int MODE>
__global__ __launch_bounds__(256) void gemm64(
    const bf16* __restrict__ A, const bf16* __restrict__ Bt,
    void* __restrict__ Cout, int K, int N,
    const float* __restrict__ shiftp, const float* __restrict__ scalep) {
  __shared__ __align__(16) bf16 As[64 * 64];
  __shared__ __align__(16) bf16 Bs[64 * 64];
  int tid = threadIdx.x;
  int lane = tid & 63, wv = tid >> 6;
  int wr = wv >> 1, wc = wv & 1;
  int quad = lane >> 4, lr = lane & 15;
  int m0 = blockIdx.y * 64, n0 = blockIdx.x * 64;
  f32x4 acc[2][2] = {};
  for (int kt = 0; kt < K; kt += 64) {
    __syncthreads();
    for (int j = 0; j < 2; j++) {
      int idx0 = j * 256 + wv * 64;
      int row = (idx0 >> 3) + (lane >> 3);
      int cb = (lane & 7) ^ (row & 7);
      async16(&A[(size_t)(m0 + row) * K + kt + cb * 8], &As[idx0 * 8]);
      async16(&Bt[(size_t)(n0 + row) * K + kt + cb * 8], &Bs[idx0 * 8]);
    }
    __syncthreads();
    for (int kk = 0; kk < 2; kk++) {
      bf16x8 af[2], bfr[2];
      for (int im = 0; im < 2; im++) {
        int row = wr * 32 + im * 16 + lr;
        af[im] = *(const bf16x8*)&As[row * 64 + ((quad + 4 * kk) ^ (row & 7)) * 8];
      }
      for (int in = 0; in < 2; in++) {
        int row = wc * 32 + in * 16 + lr;
        bfr[in] = *(const bf16x8*)&Bs[row * 64 + ((quad + 4 * kk) ^ (row & 7)) * 8];
      }
      for (int im = 0; im < 2; im++)
        for (int in = 0; in < 2; in++)
          acc[im][in] = __builtin_amdgcn_mfma_f32_16x16x32_bf16(
              af[im], bfr[in], acc[im][in], 0, 0, 0);
    }
  }
  for (int im = 0; im < 2; im++)
    for (int in = 0; in < 2; in++) {
      int col = n0 + wc * 32 + in * 16 + lr;
      for (int r = 0; r < 4; r++) {
        int row = m0 + wr * 32 + im * 16 + quad * 4 + r;
        float v = acc[im][in][r];
        if (MODE == 1) {
          int bb = row >> 8, hh = col >> 6;
          float sc = scalep[bb * 16 + hh], sh = shiftp[bb * 16 + hh];
          ((bf16*)Cout)[(size_t)row * N + col] =
              (bf16)((v * (1.0f + sc) + sh) * 0.18033688011112042f);
        } else {
          ((float*)Cout)[(size_t)row * N + col] = v;
        }
      }
    }
}

// ---------------------------------------------------------------------------
// Flash attention: double-buffered K/V staging with counted vmcnt.
// Per key-tile: {hoist ak/bv from buf[cur]; issue stage(t+1 -> buf[cur^1]);
// compute (long); vmcnt(0) [free: stage had whole compute to land]; barrier}.
// Replaces the old sync/stage/sync pair whose implicit vmcnt(0) drain
// exposed full HBM latency every tile.
// ---------------------------------------------------------------------------
__global__ __launch_bounds__(256) void attn_kernel(const bf16* __restrict__ q,
                                                   const bf16* __restrict__ kb,
                                                   const bf16* __restrict__ vt,
                                                   bf16* __restrict__ opb,
                                                   float* __restrict__ lseb) {
  int b = blockIdx.z, h = blockIdx.y;
  int qp = blockIdx.x >> 2, sp = blockIdx.x & 3;
  int tid = threadIdx.x, lane = tid & 63, wv = tid >> 6;
  int quad = lane >> 4, lr = lane & 15;
  __shared__ __align__(16) bf16 Ks[2][64 * 64];
  __shared__ __align__(16) bf16 Vs[2][64 * 64];   // [dh][key]
  __shared__ __align__(16) bf16 QP[128 * 64];     // 128 Q rows; P overlays own rows
  __shared__ float abuf[4][16];
  int q0 = qp * 128;

  // stage 128 Q rows (4 async16/thread)
  const bf16* qg = q + (size_t)(b * N2 + q0) * INNER + h * DH;
  for (int j = 0; j < 4; j++) {
    int r0 = j * 32 + wv * 8;
    int r = r0 + (lane >> 3);
    async16(&qg[(size_t)r * INNER + ((lane & 7) ^ (r & 7)) * 8], &QP[r0 * 64]);
  }
  __syncthreads();
  bf16x8 aQ[2][2];
  for (int g = 0; g < 2; g++) {
    int row = wv * 32 + g * 16 + lr;
    for (int kk = 0; kk < 2; kk++)
      aQ[g][kk] = *(const bf16x8*)&QP[row * 64 + ((quad + 4 * kk) ^ (row & 7)) * 8];
  }
  float m_s[2] = {-1e30f, -1e30f}, l_s[2] = {0.0f, 0.0f};
  f32x4 oacc[2][4] = {};

  const bf16* kg = kb + (size_t)(b * N1) * 1024 + h * DH;
  const bf16* vg = vt + (size_t)((b * HEADS + h) * DH) * N1;
  bf16* Ps = QP + wv * 2048;  // wave's own 32 Q rows (Q already in regs)

  auto stageKV = [&](int t, int buf) {
    int key0 = sp * KEYS_PER_SPLIT + t * 64;
    for (int j = 0; j < 2; j++) {
      int r0 = j * 32 + wv * 8;
      int r = r0 + (lane >> 3);
      int cs = ((lane & 7) ^ (r & 7)) * 8;
      async16(&kg[(size_t)(key0 + r) * 1024 + cs], &Ks[buf][r0 * 64]);
      async16(&vg[(size_t)r * N1 + key0 + cs], &Vs[buf][r0 * 64]);
    }
  };

  // prologue: tile 0 into buf 0
  stageKV(0, 0);
  asm volatile("s_waitcnt vmcnt(0)" ::: "memory");
  __builtin_amdgcn_s_barrier();

  for (int t = 0; t < KEYS_PER_SPLIT / 64; t++) {
    int cur = t & 1;
    // hoist K/V fragments once, reuse across both q-groups
    bf16x8 ak[2][4], bv[2][4];
    for (int kk = 0; kk < 2; kk++)
      for (int nt = 0; nt < 4; nt++) {
        int row = nt * 16 + lr;
        ak[kk][nt] =
            *(const bf16x8*)&Ks[cur][row * 64 + ((quad + 4 * kk) ^ (row & 7)) * 8];
        bv[kk][nt] =
            *(const bf16x8*)&Vs[cur][row * 64 + ((quad + 4 * kk) ^ (row & 7)) * 8];
      }
    if (t + 1 < KEYS_PER_SPLIT / 64) stageKV(t + 1, cur ^ 1);

    for (int g = 0; g < 2; g++) {
      f32x4 s[4] = {};
      for (int kk = 0; kk < 2; kk++)
        for (int nt = 0; nt < 4; nt++)
          s[nt] = __builtin_amdgcn_mfma_f32_16x16x32_bf16(ak[kk][nt], aQ[g][kk],
                                                          s[nt], 0, 0, 0);
      // per-lane softmax for query = lr (16 keys in regs, reduce across quads)
      float mx = s[0][0];
      for (int nt = 0; nt < 4; nt++)
        for (int r = 0; r < 4; r++) mx = fmaxf(mx, s[nt][r]);
      mx = fmaxf(mx, __shfl_xor(mx, 16, 64));
      mx = fmaxf(mx, __shfl_xor(mx, 32, 64));
      float mn = fmaxf(m_s[g], mx);
      float al = exp2f(m_s[g] - mn);
      float p[4][4], sum = 0.0f;
      for (int nt = 0; nt < 4; nt++)
        for (int r = 0; r < 4; r++) {
          p[nt][r] = exp2f(s[nt][r] - mn);
          sum += p[nt][r];
        }
      sum += __shfl_xor(sum, 16, 64);
      sum += __shfl_xor(sum, 32, 64);
      l_s[g] = l_s[g] * al + sum;
      m_s[g] = mn;
      if (quad == 0) abuf[wv][lr] = al;

      // packed P writes: P[query=lr][key=16nt+4quad+r]
      for (int nt = 0; nt < 4; nt++) {
        bf16x4 pk;
        for (int r = 0; r < 4; r++) pk[r] = (bf16)p[nt][r];
        *(bf16x4*)&Ps[lr * 64 + ((2 * nt + (quad >> 1)) ^ (lr & 7)) * 8 +
                      (quad & 1) * 4] = pk;
      }

      // rescale O accumulator (rows = query = quad*4+r)
      f32x4 a4 = *(const f32x4*)&abuf[wv][quad * 4];
      for (int in = 0; in < 4; in++)
        for (int r = 0; r < 4; r++) oacc[g][in][r] *= a4[r];

      bf16x8 aP[2];
      for (int kk = 0; kk < 2; kk++)
        aP[kk] = *(const bf16x8*)&Ps[lr * 64 + ((4 * kk + quad) ^ (lr & 7)) * 8];
      for (int kk = 0; kk < 2; kk++)
        for (int in = 0; in < 4; in++)
          oacc[g][in] = __builtin_amdgcn_mfma_f32_16x16x32_bf16(
              aP[kk], bv[kk][in], oacc[g][in], 0, 0, 0);
    }
    // stage issued at tile start has landed (whole compute passed): free wait
    asm volatile("s_waitcnt vmcnt(0)" ::: "memory");
    __builtin_amdgcn_s_barrier();
  }

  // epilogue: normalized bf16 partials + lse
  bf16* ob = opb + (size_t)sp * SPLIT_ELEMS;
  size_t rbase = (size_t)(b * HEADS + h) * N2;
  for (int g = 0; g < 2; g++) {
    for (int r = 0; r < 4; r++) {
      float lrow = __shfl(l_s[g], quad * 4 + r, 16);
      float inv = 1.0f / lrow;
      int qq = q0 + wv * 32 + g * 16 + quad * 4 + r;
      for (int in = 0; in < 4; in++)
        ob[(rbase + qq) * 64 + in * 16 + lr] = (bf16)(oacc[g][in][r] * inv);
    }
    if (quad == 0) {
      int qq = q0 + wv * 32 + g * 16 + lr;
      lseb[(size_t)sp * ROWS_TOTAL + rbase + qq] = m_s[g] + __log2f(l_s[g]);
    }
  }
}

// ---------------------------------------------------------------------------
// Combine (unchanged)
// ---------------------------------------------------------------------------
__global__ __launch_bounds__(256) void combine_kernel(const bf16* __restrict__ opb,
                                                      const float* __restrict__ lseb,
                                                      bf16* __restrict__ out) {
  int gid = blockIdx.x * 256 + threadIdx.x;
  int d = gid & 63;
  int rq = gid >> 6;
  int qq = rq & 255, bh = rq >> 8;
  int h = bh & 15, b = bh >> 4;
  float ls[ASPLIT];
  for (int s = 0; s < ASPLIT; s++) ls[s] = lseb[(size_t)s * ROWS_TOTAL + rq];
  float M = fmaxf(fmaxf(ls[0], ls[1]), fmaxf(ls[2], ls[3]));
  float L = 0.0f, o = 0.0f;
  for (int s = 0; s < ASPLIT; s++) {
    float w = exp2f(ls[s] - M);
    L += w;
    o += w * (float)opb[(size_t)s * SPLIT_ELEMS + (size_t)rq * 64 + d];
  }
  out[((size_t)(b * N2 + qq)) * INNER + h * DH + d] = (bf16)(o / L);
}

// ---------------------------------------------------------------------------
extern "C" void kernel_launch(void* const* d_in, const int* in_sizes, int n_in,
                              void* d_out, int out_size, void* d_ws,
                              size_t ws_size, hipStream_t stream) {
  const float* x       = (const float*)d_in[0];
  const float* latents = (const float*)d_in[1];
  const float* shift   = (const float*)d_in[2];
  const float* scale   = (const float*)d_in[3];
  const float* ln1w    = (const float*)d_in[4];
  const float* ln1b    = (const float*)d_in[5];
  const float* ln2w    = (const float*)d_in[6];
  const float* ln2b    = (const float*)d_in[7];
  const float* Wq      = (const float*)d_in[8];
  const float* Wkv     = (const float*)d_in[9];
  const float* Wout    = (const float*)d_in[10];

  char* ws = (char*)d_ws;
  bf16*  xn    = (bf16*)(ws);                // 33.5MB; dead after gemm_kv
  bf16*  opb   = (bf16*)(ws);                //   overlay: 4 bf16 splits 33.5MB
  bf16*  lnl   = (bf16*)(ws + 33554432);     // 2MB; dead after q gemm
  float* lseb  = (float*)(ws + 33554432);    //   overlay: lse 256KB
  bf16*  qb    = (bf16*)(ws + 35651584);     // 2MB
  bf16*  kb    = (bf16*)(ws + 37748736);     // 33.5MB (K half)
  bf16*  vtb   = (bf16*)(ws + 104857600);    // 33.5MB (V^T)
  bf16*  aob   = (bf16*)(ws + 138412032);    // 2MB
  bf16*  WqT   = (bf16*)(ws + 140509184);    // 2MB
  bf16*  WkvT  = (bf16*)(ws + 142606336);    // 4MB
  bf16*  WoutT = (bf16*)(ws + 146800640);    // 2MB

  static bool attr_done = false;
  if (!attr_done) {
    hipFuncSetAttribute(reinterpret_cast<const void*>(gemm_kv256),
                        hipFuncAttributeMaxDynamicSharedMemorySize, 131072);
    attr_done = true;
  }

  prep<<<8448, 256, 0, stream>>>(Wq, Wkv, Wout, WqT, WkvT, WoutT, x, latents,
                                 ln1w, ln1b, ln2w, ln2b, xn, lnl);
  gemm_kv256<<<dim3(256), dim3(512), 131072, stream>>>(xn, WkvT, kb, vtb);
  gemm64<1><<<dim3(16, 16), 256, 0, stream>>>(lnl, WqT, qb, 1024, 1024, shift,
                                              scale);
  attn_kernel<<<dim3(2 * ASPLIT, 16, 4), 256, 0, stream>>>(qb, kb, vtb, opb,
                                                           lseb);
  combine_kernel<<<16384, 256, 0, stream>>>(opb, lseb, aob);
  gemm64<2><<<dim3(16, 16), 256, 0, stream>>>(aob, WoutT, d_out, 1024, 1024,
                                              nullptr, nullptr);
}

// Round 3
// 278.358 us; speedup vs baseline: 1.1293x; 1.1293x over previous
//
#include <hip/hip_runtime.h>

typedef __bf16 bf16;
typedef bf16 bf16x8 __attribute__((ext_vector_type(8)));
typedef bf16 bf16x4 __attribute__((ext_vector_type(4)));
typedef float f32x4 __attribute__((ext_vector_type(4)));

#define B_ 4
#define N1 4096
#define N2 256
#define DIM 1024
#define HEADS 16
#define DH 64
#define INNER 1024
#define ASPLIT 4
#define KEYS_PER_SPLIT (N1 / ASPLIT)      // 1024
#define SPLIT_ELEMS (4 * 16 * 256 * 64)   // elems per split partial (bf16)
#define ROWS_TOTAL (4 * HEADS * N2)       // 16384 rows per split

// async global->LDS, 16B per lane; LDS dest = wave-uniform base + lane*16
typedef __attribute__((address_space(1))) const void gvoid_t;
typedef __attribute__((address_space(3))) void lvoid_t;
__device__ __forceinline__ void async16(const void* g, void* l) {
  __builtin_amdgcn_global_load_lds((gvoid_t*)g, (lvoid_t*)l, 16, 0, 0);
}

// ---------------------------------------------------------------------------
// prep: fused weight transposes + both LayerNorms in one launch. (unchanged)
// ---------------------------------------------------------------------------
__global__ __launch_bounds__(256) void prep(
    const float* __restrict__ Wq, const float* __restrict__ Wkv,
    const float* __restrict__ Wout, bf16* __restrict__ WqT,
    bf16* __restrict__ WkvT, bf16* __restrict__ WoutT,
    const float* __restrict__ x, const float* __restrict__ latents,
    const float* __restrict__ ln1w, const float* __restrict__ ln1b,
    const float* __restrict__ ln2w, const float* __restrict__ ln2b,
    bf16* __restrict__ xn, bf16* __restrict__ lnl) {
  __shared__ float tile[32][33];
  int t = blockIdx.x;
  if (t < 4096) {  // ---- transpose path ----
    const float* src;
    bf16* dst;
    int N;
    if (t < 1024) { src = Wq; dst = WqT; N = 1024; }
    else if (t < 3072) { t -= 1024; src = Wkv; dst = WkvT; N = 2048; }
    else { t -= 3072; src = Wout; dst = WoutT; N = 1024; }
    int ntiles = N >> 5;
    int n0 = (t % ntiles) * 32, k0 = (t / ntiles) * 32;
    int xx = threadIdx.x & 31, yy = threadIdx.x >> 5;
    for (int j = 0; j < 4; j++)
      tile[yy + 8 * j][xx] = src[(size_t)(k0 + yy + 8 * j) * N + n0 + xx];
    __syncthreads();
    for (int j = 0; j < 4; j++)
      dst[(size_t)(n0 + yy + 8 * j) * 1024 + k0 + xx] = (bf16)tile[xx][yy + 8 * j];
    return;
  }
  // ---- LN path ----
  int wv = threadIdx.x >> 6, lane = threadIdx.x & 63;
  int grow = (t - 4096) * 4 + wv;
  const float *src, *w, *bb;
  bf16* dst;
  int row;
  if (grow < 16384) { src = x; w = ln1w; bb = ln1b; dst = xn; row = grow; }
  else { src = latents; w = ln2w; bb = ln2b; dst = lnl; row = grow - 16384; }
  const float4* p = (const float4*)(src + (size_t)row * DIM);
  float4 v[4];
  for (int j = 0; j < 4; j++) v[j] = p[j * 64 + lane];
  float s = 0.f, sq = 0.f;
  for (int j = 0; j < 4; j++) {
    s += v[j].x + v[j].y + v[j].z + v[j].w;
    sq += v[j].x * v[j].x + v[j].y * v[j].y + v[j].z * v[j].z + v[j].w * v[j].w;
  }
  for (int off = 32; off; off >>= 1) {
    s += __shfl_xor(s, off, 64);
    sq += __shfl_xor(sq, off, 64);
  }
  float mu = s * (1.0f / DIM);
  float var = sq * (1.0f / DIM) - mu * mu;
  float r = rsqrtf(var + 1e-5f);
  for (int j = 0; j < 4; j++) {
    float4 wv4 = ((const float4*)w)[j * 64 + lane];
    float4 bv4 = ((const float4*)bb)[j * 64 + lane];
    bf16x4 o;
    o[0] = (bf16)((v[j].x - mu) * r * wv4.x + bv4.x);
    o[1] = (bf16)((v[j].y - mu) * r * wv4.y + bv4.y);
    o[2] = (bf16)((v[j].z - mu) * r * wv4.z + bv4.z);
    o[3] = (bf16)((v[j].w - mu) * r * wv4.w + bv4.w);
    *(bf16x4*)(dst + (size_t)row * DIM + (j * 64 + lane) * 4) = o;
  }
}

// ---------------------------------------------------------------------------
// Big GEMM (kv): 256x256 tile, BK=64, 8-phase schedule with counted vmcnt.
// (REVERTED to the round-1 version verbatim: 76.0 us verified. Round-2's
// paired-tile + direct V stores caused 2.2x write amplification and L2
// thrash; the LDS-transpose epilogue and 512-block grid are restored.)
// ---------------------------------------------------------------------------
__device__ __forceinline__ int swz_off(int row, int cb) {
  int line = row >> 1;
  return (line << 7) + (((((row & 1) << 2) | cb) ^ (line & 7)) << 4);
}

__global__ __launch_bounds__(512, 2) void gemm_kv256(
    const bf16* __restrict__ A, const bf16* __restrict__ Bt,
    bf16* __restrict__ Cout, bf16* __restrict__ Cout2) {
  extern __shared__ char smem[];
  int tid = threadIdx.x;
  int lane = tid & 63, wv = tid >> 6;
  int lr = lane & 15, quad = lane >> 4;
  int wr = wv >> 2, wc = wv & 3;
  int bid = blockIdx.x;  // 512 blocks; XCD-bijective remap (512 % 8 == 0)
  int mt = (bid & 7) * 8 + ((bid >> 3) >> 3), nt = (bid >> 3) & 7;
  int m0 = mt * 256, n0 = nt * 256;

  // fragment byte-offsets within a khalf tile
  int offA[8], offB[4];
#pragma unroll
  for (int im = 0; im < 8; im++) offA[im] = swz_off(wr * 128 + im * 16 + lr, quad);
#pragma unroll
  for (int in = 0; in < 4; in++) offB[in] = swz_off(wc * 64 + in * 16 + lr, quad);

  // staging: unit u = s*512+tid holds logical (row, cb) of the khalf tile
  size_t gA[2], gB[2];
#pragma unroll
  for (int s = 0; s < 2; s++) {
    int u = s * 512 + tid;
    int line = u >> 3, inner = (u & 7) ^ (line & 7);
    int row = line * 2 + (inner >> 2), cb = inner & 3;
    gA[s] = (size_t)(m0 + row) * 1024 + cb * 8;
    gB[s] = (size_t)(n0 + row) * 1024 + cb * 8;
  }
  int ldsS0 = wv * 1024, ldsS1 = 8192 + wv * 1024;  // wave-uniform LDS dests

  auto stA = [&](int b, int kh, int k0) {
    char* base = smem + b * 32768 + kh * 16384;
    async16(&A[gA[0] + k0], base + ldsS0);
    async16(&A[gA[1] + k0], base + ldsS1);
  };
  auto stB = [&](int b, int kh, int k0) {
    char* base = smem + 65536 + b * 32768 + kh * 16384;
    async16(&Bt[gB[0] + k0], base + ldsS0);
    async16(&Bt[gB[1] + k0], base + ldsS1);
  };

  f32x4 acc[8][4] = {};

  // prologue: tile0 (kh0,kh1) + tile1 kh0; allow tile1-kh0's 4 loads in flight
  stA(0, 0, 0);  stB(0, 0, 0);
  stA(0, 1, 32); stB(0, 1, 32);
  stA(1, 0, 64); stB(1, 0, 64);
  asm volatile("s_waitcnt vmcnt(4)" ::: "memory");
  __builtin_amdgcn_s_barrier();

#pragma unroll 1
  for (int t = 0; t < 16; t++) {
    int b = t & 1;
    const char* A0 = smem + b * 32768;
    const char* A1 = A0 + 16384;
    const char* B0 = smem + 65536 + b * 32768;
    const char* B1 = B0 + 16384;
    // clamped tails restage identical bytes -> harmless, keeps vmcnt uniform
    int k1 = (t + 1 < 16 ? t + 1 : 15) * 64;
    int k2 = (t + 2 < 16 ? t + 2 : 15) * 64;
    bf16x8 af[4], bfr[4];
    // ---- P1: kh0, mh0 ----
#pragma unroll
    for (int in = 0; in < 4; in++) bfr[in] = *(const bf16x8*)(B0 + offB[in]);
#pragma unroll
    for (int im = 0; im < 4; im++) af[im] = *(const bf16x8*)(A0 + offA[im]);
    stA(b ^ 1, 1, k1 + 32);
    __builtin_amdgcn_s_barrier();
    __builtin_amdgcn_s_setprio(1);
#pragma unroll
    for (int im = 0; im < 4; im++)
#pragma unroll
      for (int in = 0; in < 4; in++)
        acc[im][in] = __builtin_amdgcn_mfma_f32_16x16x32_bf16(
            af[im], bfr[in], acc[im][in], 0, 0, 0);
    __builtin_amdgcn_s_setprio(0);
    __builtin_amdgcn_s_barrier();
    // ---- P2: kh0, mh1 ----
#pragma unroll
    for (int im = 0; im < 4; im++) af[im] = *(const bf16x8*)(A0 + offA[4 + im]);
    stB(b ^ 1, 1, k1 + 32);
    __builtin_amdgcn_s_barrier();
    __builtin_amdgcn_s_setprio(1);
#pragma unroll
    for (int im = 0; im < 4; im++)
#pragma unroll
      for (int in = 0; in < 4; in++)
        acc[4 + im][in] = __builtin_amdgcn_mfma_f32_16x16x32_bf16(
            af[im], bfr[in], acc[4 + im][in], 0, 0, 0);
    __builtin_amdgcn_s_setprio(0);
    __builtin_amdgcn_s_barrier();
    // ---- P3: kh1, mh0 ----
#pragma unroll
    for (int in = 0; in < 4; in++) bfr[in] = *(const bf16x8*)(B1 + offB[in]);
#pragma unroll
    for (int im = 0; im < 4; im++) af[im] = *(const bf16x8*)(A1 + offA[im]);
    stA(b, 0, k2);  // kh0 of this buffer: fully read at P1/P2, freed by P2's barrier
    __builtin_amdgcn_s_barrier();
    __builtin_amdgcn_s_setprio(1);
#pragma unroll
    for (int im = 0; im < 4; im++)
#pragma unroll
      for (int in = 0; in < 4; in++)
        acc[im][in] = __builtin_amdgcn_mfma_f32_16x16x32_bf16(
            af[im], bfr[in], acc[im][in], 0, 0, 0);
    __builtin_amdgcn_s_setprio(0);
    __builtin_amdgcn_s_barrier();
    // ---- P4: kh1, mh1 ----
#pragma unroll
    for (int im = 0; im < 4; im++) af[im] = *(const bf16x8*)(A1 + offA[4 + im]);
    stB(b, 0, k2);
    __builtin_amdgcn_s_barrier();
    __builtin_amdgcn_s_setprio(1);
#pragma unroll
    for (int im = 0; im < 4; im++)
#pragma unroll
      for (int in = 0; in < 4; in++)
        acc[4 + im][in] = __builtin_amdgcn_mfma_f32_16x16x32_bf16(
            af[im], bfr[in], acc[4 + im][in], 0, 0, 0);
    __builtin_amdgcn_s_setprio(0);
    // counted guard BEFORE the tile-end barrier: all but the newest 4 loads
    // (P3+P4 stages) have landed in every wave; barrier publishes cross-wave.
    asm volatile("s_waitcnt vmcnt(4)" ::: "memory");
    __builtin_amdgcn_s_barrier();
  }

  // drain remaining in-flight stages before reusing LDS in the epilogue
  asm volatile("s_waitcnt vmcnt(0)" ::: "memory");
  __builtin_amdgcn_s_barrier();

  if (n0 < 1024) {
    // K half: direct bf16 stores (L2 combines the 16-lane segments)
#pragma unroll
    for (int im = 0; im < 8; im++)
#pragma unroll
      for (int in = 0; in < 4; in++) {
        int col = n0 + wc * 64 + in * 16 + lr;
#pragma unroll
        for (int r = 0; r < 4; r++) {
          int row = m0 + wr * 128 + im * 16 + quad * 4 + r;
          Cout[(size_t)row * 1024 + col] = (bf16)acc[im][in][r];
        }
      }
    return;
  }
  // V half: per-wave LDS transpose (own 8704B region), b128 stores along key
  int b2 = m0 >> 12;
  int key0 = (m0 & 4095) + wr * 128;
  int gc0 = (n0 - 1024) + wc * 64;
  bf16* Tw = (bf16*)(smem + wv * 8704);  // [32 cols][136 keys pitch]
  for (int pass = 0; pass < 2; pass++) {
#pragma unroll
    for (int ii = 0; ii < 2; ii++) {
      int in = pass * 2 + ii;
      int cl = ii * 16 + lr;
#pragma unroll
      for (int im = 0; im < 8; im++) {
        bf16x4 pk;
#pragma unroll
        for (int r = 0; r < 4; r++) pk[r] = (bf16)acc[im][in][r];
        *(bf16x4*)&Tw[cl * 136 + im * 16 + quad * 4] = pk;
      }
    }
    asm volatile("s_waitcnt lgkmcnt(0)" ::: "memory");
#pragma unroll
    for (int j = 0; j < 8; j++) {
      int idx = j * 64 + lane;
      int cl = idx >> 4, k8 = idx & 15;
      uint4 val = *(const uint4*)&Tw[cl * 136 + k8 * 8];
      *(uint4*)&Cout2[((size_t)(b2 * 1024 + gc0 + pass * 32 + cl)) * 4096 +
                      key0 + k8 * 8] = val;
    }
    asm volatile("s_waitcnt lgkmcnt(0)" ::: "memory");
  }
}

// ---------------------------------------------------------------------------
// Small GEMM: 64x64 tile, BK=64, 3-buffer rotation with counted vmcnt.
// Step s: read frags from buf[s%3]; issue stage(s+2)->buf[(s+2)%3]; MFMA;
// vmcnt(4) (stage(s+1) proven landed; stage(s+2)'s 4 loads stay in flight);
// barrier. WAR safe: buf[(s+2)%3] == buf[(s-1)%3], read before the end-of-
// (s-1) barrier. Tail restages step 15 into dead buffers (uniform vmcnt).
// Replaces sync->stage->sync whose full drain exposed HBM latency per step.
// ---------------------------------------------------------------------------
template <int MODE>
__global__ __launch_bounds__(256) void gemm64(
    const bf16* __restrict__ A, const bf16* __restrict__ Bt,
    void* __restrict__ Cout, int K, int N,
    const float* __restrict__ shiftp, const float* __restrict__ scalep) {
  __shared__ __align__(16) bf16 As[3][64 * 64];
  __shared__ __align__(16) bf16 Bs[3][64 * 64];
  int tid = threadIdx.x;
  int lane = tid & 63, wv = tid >> 6;
  int wr = wv >> 1, wc = wv & 1;
  int quad = lane >> 4, lr = lane & 15;
  int m0 = blockIdx.y * 64, n0 = blockIdx.x * 64;
  f32x4 acc[2][2] = {};

  auto stage = [&](int step, int buf) {
    int kt = step * 64;
    for (int j = 0; j < 2; j++) {
      int idx0 = j * 256 + wv * 64;
      int row = (idx0 >> 3) + (lane >> 3);
      int cb = (lane & 7) ^ (row & 7);
      async16(&A[(size_t)(m0 + row) * K + kt + cb * 8], &As[buf][idx0 * 8]);
      async16(&Bt[(size_t)(n0 + row) * K + kt + cb * 8], &Bs[buf][idx0 * 8]);
    }
  };

  int nsteps = K >> 6;  // 16
  // prologue: stage step0->buf0, step1->buf1; wait step0 (newest 4 in flight)
  stage(0, 0);
  stage(1, 1);
  asm volatile("s_waitcnt vmcnt(4)" ::: "memory");
  __builtin_amdgcn_s_barrier();

#pragma unroll 1
  for (int s = 0; s < nsteps; s++) {
    int cur = s % 3;
    int nxt = (s + 2 < nsteps) ? s + 2 : nsteps - 1;  // tail: dead restage
    stage(nxt, (s + 2) % 3);
    for (int kk = 0; kk < 2; kk++) {
      bf16x8 af[2], bfr[2];
      for (int im = 0; im < 2; im++) {
        int row = wr * 32 + im * 16 + lr;
        af[im] =
            *(const bf16x8*)&As[cur][row * 64 + ((quad + 4 * kk) ^ (row & 7)) * 8];
      }
      for (int in = 0; in < 2; in++) {
        int row = wc * 32 + in * 16 + lr;
        bfr[in] =
            *(const bf16x8*)&Bs[cur][row * 64 + ((quad + 4 * kk) ^ (row & 7)) * 8];
      }
      for (int im = 0; im < 2; im++)
        for (int in = 0; in < 2; in++)
          acc[im][in] = __builtin_amdgcn_mfma_f32_16x16x32_bf16(
              af[im], bfr[in], acc[im][in], 0, 0, 0);
    }
    // stage(s+1) landed (only stage(s+2)'s 4 loads remain); publish cross-wave
    asm volatile("s_waitcnt vmcnt(4)" ::: "memory");
    __builtin_amdgcn_s_barrier();
  }

  for (int im = 0; im < 2; im++)
    for (int in = 0; in < 2; in++) {
      int col = n0 + wc * 32 + in * 16 + lr;
      for (int r = 0; r < 4; r++) {
        int row = m0 + wr * 32 + im * 16 + quad * 4 + r;
        float v = acc[im][in][r];
        if (MODE == 1) {
          int bb = row >> 8, hh = col >> 6;
          float sc = scalep[bb * 16 + hh], sh = shiftp[bb * 16 + hh];
          ((bf16*)Cout)[(size_t)row * N + col] =
              (bf16)((v * (1.0f + sc) + sh) * 0.18033688011112042f);
        } else {
          ((float*)Cout)[(size_t)row * N + col] = v;
        }
      }
    }
}

// ---------------------------------------------------------------------------
// Flash attention: double-buffered K/V staging with counted vmcnt. (round-2
// version, kept: neutral-to-positive; structurally removes per-tile drain)
// ---------------------------------------------------------------------------
__global__ __launch_bounds__(256) void attn_kernel(const bf16* __restrict__ q,
                                                   const bf16* __restrict__ kb,
                                                   const bf16* __restrict__ vt,
                                                   bf16* __restrict__ opb,
                                                   float* __restrict__ lseb) {
  int b = blockIdx.z, h = blockIdx.y;
  int qp = blockIdx.x >> 2, sp = blockIdx.x & 3;
  int tid = threadIdx.x, lane = tid & 63, wv = tid >> 6;
  int quad = lane >> 4, lr = lane & 15;
  __shared__ __align__(16) bf16 Ks[2][64 * 64];
  __shared__ __align__(16) bf16 Vs[2][64 * 64];   // [dh][key]
  __shared__ __align__(16) bf16 QP[128 * 64];     // 128 Q rows; P overlays own rows
  __shared__ float abuf[4][16];
  int q0 = qp * 128;

  // stage 128 Q rows (4 async16/thread)
  const bf16* qg = q + (size_t)(b * N2 + q0) * INNER + h * DH;
  for (int j = 0; j < 4; j++) {
    int r0 = j * 32 + wv * 8;
    int r = r0 + (lane >> 3);
    async16(&qg[(size_t)r * INNER + ((lane & 7) ^ (r & 7)) * 8], &QP[r0 * 64]);
  }
  __syncthreads();
  bf16x8 aQ[2][2];
  for (int g = 0; g < 2; g++) {
    int row = wv * 32 + g * 16 + lr;
    for (int kk = 0; kk < 2; kk++)
      aQ[g][kk] = *(const bf16x8*)&QP[row * 64 + ((quad + 4 * kk) ^ (row & 7)) * 8];
  }
  float m_s[2] = {-1e30f, -1e30f}, l_s[2] = {0.0f, 0.0f};
  f32x4 oacc[2][4] = {};

  const bf16* kg = kb + (size_t)(b * N1) * 1024 + h * DH;
  const bf16* vg = vt + (size_t)((b * HEADS + h) * DH) * N1;
  bf16* Ps = QP + wv * 2048;  // wave's own 32 Q rows (Q already in regs)

  auto stageKV = [&](int t, int buf) {
    int key0 = sp * KEYS_PER_SPLIT + t * 64;
    for (int j = 0; j < 2; j++) {
      int r0 = j * 32 + wv * 8;
      int r = r0 + (lane >> 3);
      int cs = ((lane & 7) ^ (r & 7)) * 8;
      async16(&kg[(size_t)(key0 + r) * 1024 + cs], &Ks[buf][r0 * 64]);
      async16(&vg[(size_t)r * N1 + key0 + cs], &Vs[buf][r0 * 64]);
    }
  };

  // prologue: tile 0 into buf 0
  stageKV(0, 0);
  asm volatile("s_waitcnt vmcnt(0)" ::: "memory");
  __builtin_amdgcn_s_barrier();

  for (int t = 0; t < KEYS_PER_SPLIT / 64; t++) {
    int cur = t & 1;
    // hoist K/V fragments once, reuse across both q-groups
    bf16x8 ak[2][4], bv[2][4];
    for (int kk = 0; kk < 2; kk++)
      for (int nt = 0; nt < 4; nt++) {
        int row = nt * 16 + lr;
        ak[kk][nt] =
            *(const bf16x8*)&Ks[cur][row * 64 + ((quad + 4 * kk) ^ (row & 7)) * 8];
        bv[kk][nt] =
            *(const bf16x8*)&Vs[cur][row * 64 + ((quad + 4 * kk) ^ (row & 7)) * 8];
      }
    if (t + 1 < KEYS_PER_SPLIT / 64) stageKV(t + 1, cur ^ 1);

    for (int g = 0; g < 2; g++) {
      f32x4 s[4] = {};
      for (int kk = 0; kk < 2; kk++)
        for (int nt = 0; nt < 4; nt++)
          s[nt] = __builtin_amdgcn_mfma_f32_16x16x32_bf16(ak[kk][nt], aQ[g][kk],
                                                          s[nt], 0, 0, 0);
      // per-lane softmax for query = lr (16 keys in regs, reduce across quads)
      float mx = s[0][0];
      for (int nt = 0; nt < 4; nt++)
        for (int r = 0; r < 4; r++) mx = fmaxf(mx, s[nt][r]);
      mx = fmaxf(mx, __shfl_xor(mx, 16, 64));
      mx = fmaxf(mx, __shfl_xor(mx, 32, 64));
      float mn = fmaxf(m_s[g], mx);
      float al = exp2f(m_s[g] - mn);
      float p[4][4], sum = 0.0f;
      for (int nt = 0; nt < 4; nt++)
        for (int r = 0; r < 4; r++) {
          p[nt][r] = exp2f(s[nt][r] - mn);
          sum += p[nt][r];
        }
      sum += __shfl_xor(sum, 16, 64);
      sum += __shfl_xor(sum, 32, 64);
      l_s[g] = l_s[g] * al + sum;
      m_s[g] = mn;
      if (quad == 0) abuf[wv][lr] = al;

      // packed P writes: P[query=lr][key=16nt+4quad+r]
      for (int nt = 0; nt < 4; nt++) {
        bf16x4 pk;
        for (int r = 0; r < 4; r++) pk[r] = (bf16)p[nt][r];
        *(bf16x4*)&Ps[lr * 64 + ((2 * nt + (quad >> 1)) ^ (lr & 7)) * 8 +
                      (quad & 1) * 4] = pk;
      }

      // rescale O accumulator (rows = query = quad*4+r)
      f32x4 a4 = *(const f32x4*)&abuf[wv][quad * 4];
      for (int in = 0; in < 4; in++)
        for (int r = 0; r < 4; r++) oacc[g][in][r] *= a4[r];

      bf16x8 aP[2];
      for (int kk = 0; kk < 2; kk++)
        aP[kk] = *(const bf16x8*)&Ps[lr * 64 + ((4 * kk + quad) ^ (lr & 7)) * 8];
      for (int kk = 0; kk < 2; kk++)
        for (int in = 0; in < 4; in++)
          oacc[g][in] = __builtin_amdgcn_mfma_f32_16x16x32_bf16(
              aP[kk], bv[kk][in], oacc[g][in], 0, 0, 0);
    }
    // stage issued at tile start has landed (whole compute passed): free wait
    asm volatile("s_waitcnt vmcnt(0)" ::: "memory");
    __builtin_amdgcn_s_barrier();
  }

  // epilogue: normalized bf16 partials + lse
  bf16* ob = opb + (size_t)sp * SPLIT_ELEMS;
  size_t rbase = (size_t)(b * HEADS + h) * N2;
  for (int g = 0; g < 2; g++) {
    for (int r = 0; r < 4; r++) {
      float lrow = __shfl(l_s[g], quad * 4 + r, 16);
      float inv = 1.0f / lrow;
      int qq = q0 + wv * 32 + g * 16 + quad * 4 + r;
      for (int in = 0; in < 4; in++)
        ob[(rbase + qq) * 64 + in * 16 + lr] = (bf16)(oacc[g][in][r] * inv);
    }
    if (quad == 0) {
      int qq = q0 + wv * 32 + g * 16 + lr;
      lseb[(size_t)sp * ROWS_TOTAL + rbase + qq] = m_s[g] + __log2f(l_s[g]);
    }
  }
}

// ---------------------------------------------------------------------------
// Combine (unchanged)
// ---------------------------------------------------------------------------
__global__ __launch_bounds__(256) void combine_kernel(const bf16* __restrict__ opb,
                                                      const float* __restrict__ lseb,
                                                      bf16* __restrict__ out) {
  int gid = blockIdx.x * 256 + threadIdx.x;
  int d = gid & 63;
  int rq = gid >> 6;  // (b*16+h)*256 + q
  int qq = rq & 255, bh = rq >> 8;
  int h = bh & 15, b = bh >> 4;
  float ls[ASPLIT];
  for (int s = 0; s < ASPLIT; s++) ls[s] = lseb[(size_t)s * ROWS_TOTAL + rq];
  float M = fmaxf(fmaxf(ls[0], ls[1]), fmaxf(ls[2], ls[3]));
  float L = 0.0f, o = 0.0f;
  for (int s = 0; s < ASPLIT; s++) {
    float w = exp2f(ls[s] - M);
    L += w;
    o += w * (float)opb[(size_t)s * SPLIT_ELEMS + (size_t)rq * 64 + d];
  }
  out[((size_t)(b * N2 + qq)) * INNER + h * DH + d] = (bf16)(o / L);
}

// ---------------------------------------------------------------------------
extern "C" void kernel_launch(void* const* d_in, const int* in_sizes, int n_in,
                              void* d_out, int out_size, void* d_ws,
                              size_t ws_size, hipStream_t stream) {
  const float* x       = (const float*)d_in[0];
  const float* latents = (const float*)d_in[1];
  const float* shift   = (const float*)d_in[2];
  const float* scale   = (const float*)d_in[3];
  const float* ln1w    = (const float*)d_in[4];
  const float* ln1b    = (const float*)d_in[5];
  const float* ln2w    = (const float*)d_in[6];
  const float* ln2b    = (const float*)d_in[7];
  const float* Wq      = (const float*)d_in[8];
  const float* Wkv     = (const float*)d_in[9];
  const float* Wout    = (const float*)d_in[10];

  char* ws = (char*)d_ws;
  bf16*  xn    = (bf16*)(ws);                // 32MiB; dead after gemm_kv
  bf16*  opb   = (bf16*)(ws);                //   overlay: 4 bf16 splits 8MiB
  bf16*  lnl   = (bf16*)(ws + 33554432);     // 2MB; dead after q gemm
  float* lseb  = (float*)(ws + 33554432);    //   overlay: lse 256KB
  bf16*  qb    = (bf16*)(ws + 35651584);     // 2MB
  bf16*  kb    = (bf16*)(ws + 37748736);     // 32MiB (K half)
  bf16*  vtb   = (bf16*)(ws + 104857600);    // 32MiB (V^T)
  bf16*  aob   = (bf16*)(ws + 138412032);    // 2MB
  bf16*  WqT   = (bf16*)(ws + 140509184);    // 2MB
  bf16*  WkvT  = (bf16*)(ws + 142606336);    // 4MB
  bf16*  WoutT = (bf16*)(ws + 146800640);    // 2MB

  static bool attr_done = false;
  if (!attr_done) {
    hipFuncSetAttribute(reinterpret_cast<const void*>(gemm_kv256),
                        hipFuncAttributeMaxDynamicSharedMemorySize, 131072);
    attr_done = true;
  }

  prep<<<8448, 256, 0, stream>>>(Wq, Wkv, Wout, WqT, WkvT, WoutT, x, latents,
                                 ln1w, ln1b, ln2w, ln2b, xn, lnl);
  gemm_kv256<<<dim3(512), dim3(512), 131072, stream>>>(xn, WkvT, kb, vtb);
  gemm64<1><<<dim3(16, 16), 256, 0, stream>>>(lnl, WqT, qb, 1024, 1024, shift,
                                              scale);
  attn_kernel<<<dim3(2 * ASPLIT, 16, 4), 256, 0, stream>>>(qb, kb, vtb, opb,
                                                           lseb);
  combine_kernel<<<16384, 256, 0, stream>>>(opb, lseb, aob);
  gemm64<2><<<dim3(16, 16), 256, 0, stream>>>(aob, WoutT, d_out, 1024, 1024,
                                              nullptr, nullptr);
}

// Round 4
// 271.951 us; speedup vs baseline: 1.1559x; 1.0236x over previous
//
#include <hip/hip_runtime.h>

typedef __bf16 bf16;
typedef bf16 bf16x8 __attribute__((ext_vector_type(8)));
typedef bf16 bf16x4 __attribute__((ext_vector_type(4)));
typedef float f32x4 __attribute__((ext_vector_type(4)));

#define B_ 4
#define N1 4096
#define N2 256
#define DIM 1024
#define HEADS 16
#define DH 64
#define INNER 1024
#define ASPLIT 4
#define KEYS_PER_SPLIT (N1 / ASPLIT)      // 1024
#define SPLIT_ELEMS (4 * 16 * 256 * 64)   // elems per split partial (bf16)
#define ROWS_TOTAL (4 * HEADS * N2)       // 16384 rows per split

// async global->LDS, 16B per lane; LDS dest = wave-uniform base + lane*16
typedef __attribute__((address_space(1))) const void gvoid_t;
typedef __attribute__((address_space(3))) void lvoid_t;
__device__ __forceinline__ void async16(const void* g, void* l) {
  __builtin_amdgcn_global_load_lds((gvoid_t*)g, (lvoid_t*)l, 16, 0, 0);
}

// ---------------------------------------------------------------------------
// prep: fused weight transposes + both LayerNorms in one launch. (unchanged)
// ---------------------------------------------------------------------------
__global__ __launch_bounds__(256) void prep(
    const float* __restrict__ Wq, const float* __restrict__ Wkv,
    const float* __restrict__ Wout, bf16* __restrict__ WqT,
    bf16* __restrict__ WkvT, bf16* __restrict__ WoutT,
    const float* __restrict__ x, const float* __restrict__ latents,
    const float* __restrict__ ln1w, const float* __restrict__ ln1b,
    const float* __restrict__ ln2w, const float* __restrict__ ln2b,
    bf16* __restrict__ xn, bf16* __restrict__ lnl) {
  __shared__ float tile[32][33];
  int t = blockIdx.x;
  if (t < 4096) {  // ---- transpose path ----
    const float* src;
    bf16* dst;
    int N;
    if (t < 1024) { src = Wq; dst = WqT; N = 1024; }
    else if (t < 3072) { t -= 1024; src = Wkv; dst = WkvT; N = 2048; }
    else { t -= 3072; src = Wout; dst = WoutT; N = 1024; }
    int ntiles = N >> 5;
    int n0 = (t % ntiles) * 32, k0 = (t / ntiles) * 32;
    int xx = threadIdx.x & 31, yy = threadIdx.x >> 5;
    for (int j = 0; j < 4; j++)
      tile[yy + 8 * j][xx] = src[(size_t)(k0 + yy + 8 * j) * N + n0 + xx];
    __syncthreads();
    for (int j = 0; j < 4; j++)
      dst[(size_t)(n0 + yy + 8 * j) * 1024 + k0 + xx] = (bf16)tile[xx][yy + 8 * j];
    return;
  }
  // ---- LN path ----
  int wv = threadIdx.x >> 6, lane = threadIdx.x & 63;
  int grow = (t - 4096) * 4 + wv;
  const float *src, *w, *bb;
  bf16* dst;
  int row;
  if (grow < 16384) { src = x; w = ln1w; bb = ln1b; dst = xn; row = grow; }
  else { src = latents; w = ln2w; bb = ln2b; dst = lnl; row = grow - 16384; }
  const float4* p = (const float4*)(src + (size_t)row * DIM);
  float4 v[4];
  for (int j = 0; j < 4; j++) v[j] = p[j * 64 + lane];
  float s = 0.f, sq = 0.f;
  for (int j = 0; j < 4; j++) {
    s += v[j].x + v[j].y + v[j].z + v[j].w;
    sq += v[j].x * v[j].x + v[j].y * v[j].y + v[j].z * v[j].z + v[j].w * v[j].w;
  }
  for (int off = 32; off; off >>= 1) {
    s += __shfl_xor(s, off, 64);
    sq += __shfl_xor(sq, off, 64);
  }
  float mu = s * (1.0f / DIM);
  float var = sq * (1.0f / DIM) - mu * mu;
  float r = rsqrtf(var + 1e-5f);
  for (int j = 0; j < 4; j++) {
    float4 wv4 = ((const float4*)w)[j * 64 + lane];
    float4 bv4 = ((const float4*)bb)[j * 64 + lane];
    bf16x4 o;
    o[0] = (bf16)((v[j].x - mu) * r * wv4.x + bv4.x);
    o[1] = (bf16)((v[j].y - mu) * r * wv4.y + bv4.y);
    o[2] = (bf16)((v[j].z - mu) * r * wv4.z + bv4.z);
    o[3] = (bf16)((v[j].w - mu) * r * wv4.w + bv4.w);
    *(bf16x4*)(dst + (size_t)row * DIM + (j * 64 + lane) * 4) = o;
  }
}

// ---------------------------------------------------------------------------
// Big GEMM (kv): 256x256 tile, BK=64, 8-phase schedule with counted vmcnt.
// (round-1 version verbatim: 75-76 us verified)
// ---------------------------------------------------------------------------
__device__ __forceinline__ int swz_off(int row, int cb) {
  int line = row >> 1;
  return (line << 7) + (((((row & 1) << 2) | cb) ^ (line & 7)) << 4);
}

__global__ __launch_bounds__(512, 2) void gemm_kv256(
    const bf16* __restrict__ A, const bf16* __restrict__ Bt,
    bf16* __restrict__ Cout, bf16* __restrict__ Cout2) {
  extern __shared__ char smem[];
  int tid = threadIdx.x;
  int lane = tid & 63, wv = tid >> 6;
  int lr = lane & 15, quad = lane >> 4;
  int wr = wv >> 2, wc = wv & 3;
  int bid = blockIdx.x;  // 512 blocks; XCD-bijective remap (512 % 8 == 0)
  int mt = (bid & 7) * 8 + ((bid >> 3) >> 3), nt = (bid >> 3) & 7;
  int m0 = mt * 256, n0 = nt * 256;

  // fragment byte-offsets within a khalf tile
  int offA[8], offB[4];
#pragma unroll
  for (int im = 0; im < 8; im++) offA[im] = swz_off(wr * 128 + im * 16 + lr, quad);
#pragma unroll
  for (int in = 0; in < 4; in++) offB[in] = swz_off(wc * 64 + in * 16 + lr, quad);

  // staging: unit u = s*512+tid holds logical (row, cb) of the khalf tile
  size_t gA[2], gB[2];
#pragma unroll
  for (int s = 0; s < 2; s++) {
    int u = s * 512 + tid;
    int line = u >> 3, inner = (u & 7) ^ (line & 7);
    int row = line * 2 + (inner >> 2), cb = inner & 3;
    gA[s] = (size_t)(m0 + row) * 1024 + cb * 8;
    gB[s] = (size_t)(n0 + row) * 1024 + cb * 8;
  }
  int ldsS0 = wv * 1024, ldsS1 = 8192 + wv * 1024;  // wave-uniform LDS dests

  auto stA = [&](int b, int kh, int k0) {
    char* base = smem + b * 32768 + kh * 16384;
    async16(&A[gA[0] + k0], base + ldsS0);
    async16(&A[gA[1] + k0], base + ldsS1);
  };
  auto stB = [&](int b, int kh, int k0) {
    char* base = smem + 65536 + b * 32768 + kh * 16384;
    async16(&Bt[gB[0] + k0], base + ldsS0);
    async16(&Bt[gB[1] + k0], base + ldsS1);
  };

  f32x4 acc[8][4] = {};

  // prologue: tile0 (kh0,kh1) + tile1 kh0; allow tile1-kh0's 4 loads in flight
  stA(0, 0, 0);  stB(0, 0, 0);
  stA(0, 1, 32); stB(0, 1, 32);
  stA(1, 0, 64); stB(1, 0, 64);
  asm volatile("s_waitcnt vmcnt(4)" ::: "memory");
  __builtin_amdgcn_s_barrier();

#pragma unroll 1
  for (int t = 0; t < 16; t++) {
    int b = t & 1;
    const char* A0 = smem + b * 32768;
    const char* A1 = A0 + 16384;
    const char* B0 = smem + 65536 + b * 32768;
    const char* B1 = B0 + 16384;
    // clamped tails restage identical bytes -> harmless, keeps vmcnt uniform
    int k1 = (t + 1 < 16 ? t + 1 : 15) * 64;
    int k2 = (t + 2 < 16 ? t + 2 : 15) * 64;
    bf16x8 af[4], bfr[4];
    // ---- P1: kh0, mh0 ----
#pragma unroll
    for (int in = 0; in < 4; in++) bfr[in] = *(const bf16x8*)(B0 + offB[in]);
#pragma unroll
    for (int im = 0; im < 4; im++) af[im] = *(const bf16x8*)(A0 + offA[im]);
    stA(b ^ 1, 1, k1 + 32);
    __builtin_amdgcn_s_barrier();
    __builtin_amdgcn_s_setprio(1);
#pragma unroll
    for (int im = 0; im < 4; im++)
#pragma unroll
      for (int in = 0; in < 4; in++)
        acc[im][in] = __builtin_amdgcn_mfma_f32_16x16x32_bf16(
            af[im], bfr[in], acc[im][in], 0, 0, 0);
    __builtin_amdgcn_s_setprio(0);
    __builtin_amdgcn_s_barrier();
    // ---- P2: kh0, mh1 ----
#pragma unroll
    for (int im = 0; im < 4; im++) af[im] = *(const bf16x8*)(A0 + offA[4 + im]);
    stB(b ^ 1, 1, k1 + 32);
    __builtin_amdgcn_s_barrier();
    __builtin_amdgcn_s_setprio(1);
#pragma unroll
    for (int im = 0; im < 4; im++)
#pragma unroll
      for (int in = 0; in < 4; in++)
        acc[4 + im][in] = __builtin_amdgcn_mfma_f32_16x16x32_bf16(
            af[im], bfr[in], acc[4 + im][in], 0, 0, 0);
    __builtin_amdgcn_s_setprio(0);
    __builtin_amdgcn_s_barrier();
    // ---- P3: kh1, mh0 ----
#pragma unroll
    for (int in = 0; in < 4; in++) bfr[in] = *(const bf16x8*)(B1 + offB[in]);
#pragma unroll
    for (int im = 0; im < 4; im++) af[im] = *(const bf16x8*)(A1 + offA[im]);
    stA(b, 0, k2);  // kh0 of this buffer: fully read at P1/P2, freed by P2's barrier
    __builtin_amdgcn_s_barrier();
    __builtin_amdgcn_s_setprio(1);
#pragma unroll
    for (int im = 0; im < 4; im++)
#pragma unroll
      for (int in = 0; in < 4; in++)
        acc[im][in] = __builtin_amdgcn_mfma_f32_16x16x32_bf16(
            af[im], bfr[in], acc[im][in], 0, 0, 0);
    __builtin_amdgcn_s_setprio(0);
    __builtin_amdgcn_s_barrier();
    // ---- P4: kh1, mh1 ----
#pragma unroll
    for (int im = 0; im < 4; im++) af[im] = *(const bf16x8*)(A1 + offA[4 + im]);
    stB(b, 0, k2);
    __builtin_amdgcn_s_barrier();
    __builtin_amdgcn_s_setprio(1);
#pragma unroll
    for (int im = 0; im < 4; im++)
#pragma unroll
      for (int in = 0; in < 4; in++)
        acc[4 + im][in] = __builtin_amdgcn_mfma_f32_16x16x32_bf16(
            af[im], bfr[in], acc[4 + im][in], 0, 0, 0);
    __builtin_amdgcn_s_setprio(0);
    // counted guard BEFORE the tile-end barrier: all but the newest 4 loads
    // (P3+P4 stages) have landed in every wave; barrier publishes cross-wave.
    asm volatile("s_waitcnt vmcnt(4)" ::: "memory");
    __builtin_amdgcn_s_barrier();
  }

  // drain remaining in-flight stages before reusing LDS in the epilogue
  asm volatile("s_waitcnt vmcnt(0)" ::: "memory");
  __builtin_amdgcn_s_barrier();

  if (n0 < 1024) {
    // K half: direct bf16 stores (L2 combines the 16-lane segments)
#pragma unroll
    for (int im = 0; im < 8; im++)
#pragma unroll
      for (int in = 0; in < 4; in++) {
        int col = n0 + wc * 64 + in * 16 + lr;
#pragma unroll
        for (int r = 0; r < 4; r++) {
          int row = m0 + wr * 128 + im * 16 + quad * 4 + r;
          Cout[(size_t)row * 1024 + col] = (bf16)acc[im][in][r];
        }
      }
    return;
  }
  // V half: per-wave LDS transpose (own 8704B region), b128 stores along key
  int b2 = m0 >> 12;
  int key0 = (m0 & 4095) + wr * 128;
  int gc0 = (n0 - 1024) + wc * 64;
  bf16* Tw = (bf16*)(smem + wv * 8704);  // [32 cols][136 keys pitch]
  for (int pass = 0; pass < 2; pass++) {
#pragma unroll
    for (int ii = 0; ii < 2; ii++) {
      int in = pass * 2 + ii;
      int cl = ii * 16 + lr;
#pragma unroll
      for (int im = 0; im < 8; im++) {
        bf16x4 pk;
#pragma unroll
        for (int r = 0; r < 4; r++) pk[r] = (bf16)acc[im][in][r];
        *(bf16x4*)&Tw[cl * 136 + im * 16 + quad * 4] = pk;
      }
    }
    asm volatile("s_waitcnt lgkmcnt(0)" ::: "memory");
#pragma unroll
    for (int j = 0; j < 8; j++) {
      int idx = j * 64 + lane;
      int cl = idx >> 4, k8 = idx & 15;
      uint4 val = *(const uint4*)&Tw[cl * 136 + k8 * 8];
      *(uint4*)&Cout2[((size_t)(b2 * 1024 + gc0 + pass * 32 + cl)) * 4096 +
                      key0 + k8 * 8] = val;
    }
    asm volatile("s_waitcnt lgkmcnt(0)" ::: "memory");
  }
}

// ---------------------------------------------------------------------------
// Small GEMM: 64x64 tile, BK=64, 3-buffer rotation with counted vmcnt.
// (round-3 version, kept)
// ---------------------------------------------------------------------------
template <int MODE>
__global__ __launch_bounds__(256) void gemm64(
    const bf16* __restrict__ A, const bf16* __restrict__ Bt,
    void* __restrict__ Cout, int K, int N,
    const float* __restrict__ shiftp, const float* __restrict__ scalep) {
  __shared__ __align__(16) bf16 As[3][64 * 64];
  __shared__ __align__(16) bf16 Bs[3][64 * 64];
  int tid = threadIdx.x;
  int lane = tid & 63, wv = tid >> 6;
  int wr = wv >> 1, wc = wv & 1;
  int quad = lane >> 4, lr = lane & 15;
  int m0 = blockIdx.y * 64, n0 = blockIdx.x * 64;
  f32x4 acc[2][2] = {};

  auto stage = [&](int step, int buf) {
    int kt = step * 64;
    for (int j = 0; j < 2; j++) {
      int idx0 = j * 256 + wv * 64;
      int row = (idx0 >> 3) + (lane >> 3);
      int cb = (lane & 7) ^ (row & 7);
      async16(&A[(size_t)(m0 + row) * K + kt + cb * 8], &As[buf][idx0 * 8]);
      async16(&Bt[(size_t)(n0 + row) * K + kt + cb * 8], &Bs[buf][idx0 * 8]);
    }
  };

  int nsteps = K >> 6;  // 16
  stage(0, 0);
  stage(1, 1);
  asm volatile("s_waitcnt vmcnt(4)" ::: "memory");
  __builtin_amdgcn_s_barrier();

#pragma unroll 1
  for (int s = 0; s < nsteps; s++) {
    int cur = s % 3;
    int nxt = (s + 2 < nsteps) ? s + 2 : nsteps - 1;  // tail: dead restage
    stage(nxt, (s + 2) % 3);
    for (int kk = 0; kk < 2; kk++) {
      bf16x8 af[2], bfr[2];
      for (int im = 0; im < 2; im++) {
        int row = wr * 32 + im * 16 + lr;
        af[im] =
            *(const bf16x8*)&As[cur][row * 64 + ((quad + 4 * kk) ^ (row & 7)) * 8];
      }
      for (int in = 0; in < 2; in++) {
        int row = wc * 32 + in * 16 + lr;
        bfr[in] =
            *(const bf16x8*)&Bs[cur][row * 64 + ((quad + 4 * kk) ^ (row & 7)) * 8];
      }
      for (int im = 0; im < 2; im++)
        for (int in = 0; in < 2; in++)
          acc[im][in] = __builtin_amdgcn_mfma_f32_16x16x32_bf16(
              af[im], bfr[in], acc[im][in], 0, 0, 0);
    }
    asm volatile("s_waitcnt vmcnt(4)" ::: "memory");
    __builtin_amdgcn_s_barrier();
  }

  for (int im = 0; im < 2; im++)
    for (int in = 0; in < 2; in++) {
      int col = n0 + wc * 32 + in * 16 + lr;
      for (int r = 0; r < 4; r++) {
        int row = m0 + wr * 32 + im * 16 + quad * 4 + r;
        float v = acc[im][in][r];
        if (MODE == 1) {
          int bb = row >> 8, hh = col >> 6;
          float sc = scalep[bb * 16 + hh], sh = shiftp[bb * 16 + hh];
          ((bf16*)Cout)[(size_t)row * N + col] =
              (bf16)((v * (1.0f + sc) + sh) * 0.18033688011112042f);
        } else {
          ((float*)Cout)[(size_t)row * N + col] = v;
        }
      }
    }
}

// ---------------------------------------------------------------------------
// Flash attention: merged q-tiles. One 512-thread block per (b, h, split):
// 8 waves x 32 q-rows = all 256 queries -> K/V + Q staged ONCE (was twice),
// block count 512 -> 256, per-wave work unchanged. abuf LDS replaced by
// in-wave __shfl (LDS = 16K Ks + 16K Vs + 32K QP = 64 KiB exactly).
// K/V double-buffered with counted staging (issue stage(t+1) before compute;
// vmcnt(0)+barrier after -- stage had the whole compute phase to land).
// ---------------------------------------------------------------------------
__global__ __launch_bounds__(512) void attn_kernel(const bf16* __restrict__ q,
                                                   const bf16* __restrict__ kb,
                                                   const bf16* __restrict__ vt,
                                                   bf16* __restrict__ opb,
                                                   float* __restrict__ lseb) {
  int b = blockIdx.z, h = blockIdx.y;
  int sp = blockIdx.x;
  int tid = threadIdx.x, lane = tid & 63, wv = tid >> 6;
  int quad = lane >> 4, lr = lane & 15;
  __shared__ __align__(16) bf16 Ks[2][64 * 64];
  __shared__ __align__(16) bf16 Vs[2][64 * 64];   // [dh][key]
  __shared__ __align__(16) bf16 QP[256 * 64];     // 256 Q rows; P overlays own rows

  // stage all 256 Q rows (4 async16/thread, 8 waves x 8 rows per pass)
  const bf16* qg = q + (size_t)(b * N2) * INNER + h * DH;
  for (int j = 0; j < 4; j++) {
    int r0 = j * 64 + wv * 8;
    int r = r0 + (lane >> 3);
    async16(&qg[(size_t)r * INNER + ((lane & 7) ^ (r & 7)) * 8], &QP[r0 * 64]);
  }
  __syncthreads();
  bf16x8 aQ[2][2];
  for (int g = 0; g < 2; g++) {
    int row = wv * 32 + g * 16 + lr;
    for (int kk = 0; kk < 2; kk++)
      aQ[g][kk] = *(const bf16x8*)&QP[row * 64 + ((quad + 4 * kk) ^ (row & 7)) * 8];
  }
  float m_s[2] = {-1e30f, -1e30f}, l_s[2] = {0.0f, 0.0f};
  f32x4 oacc[2][4] = {};

  const bf16* kg = kb + (size_t)(b * N1) * 1024 + h * DH;
  const bf16* vg = vt + (size_t)((b * HEADS + h) * DH) * N1;
  bf16* Ps = QP + wv * 2048;  // wave's own 32 Q rows (Q already in regs)

  auto stageKV = [&](int t, int buf) {
    int key0 = sp * KEYS_PER_SPLIT + t * 64;
    int r0 = wv * 8;                 // 8 waves x 8 rows = 64 rows in one pass
    int r = r0 + (lane >> 3);
    int cs = ((lane & 7) ^ (r & 7)) * 8;
    async16(&kg[(size_t)(key0 + r) * 1024 + cs], &Ks[buf][r0 * 64]);
    async16(&vg[(size_t)r * N1 + key0 + cs], &Vs[buf][r0 * 64]);
  };

  // prologue: tile 0 into buf 0
  stageKV(0, 0);
  asm volatile("s_waitcnt vmcnt(0)" ::: "memory");
  __builtin_amdgcn_s_barrier();

  for (int t = 0; t < KEYS_PER_SPLIT / 64; t++) {
    int cur = t & 1;
    // hoist K/V fragments once, reuse across both q-groups
    bf16x8 ak[2][4], bv[2][4];
    for (int kk = 0; kk < 2; kk++)
      for (int nt = 0; nt < 4; nt++) {
        int row = nt * 16 + lr;
        ak[kk][nt] =
            *(const bf16x8*)&Ks[cur][row * 64 + ((quad + 4 * kk) ^ (row & 7)) * 8];
        bv[kk][nt] =
            *(const bf16x8*)&Vs[cur][row * 64 + ((quad + 4 * kk) ^ (row & 7)) * 8];
      }
    if (t + 1 < KEYS_PER_SPLIT / 64) stageKV(t + 1, cur ^ 1);

    for (int g = 0; g < 2; g++) {
      f32x4 s[4] = {};
      for (int kk = 0; kk < 2; kk++)
        for (int nt = 0; nt < 4; nt++)
          s[nt] = __builtin_amdgcn_mfma_f32_16x16x32_bf16(ak[kk][nt], aQ[g][kk],
                                                          s[nt], 0, 0, 0);
      // per-lane softmax for query = lr (16 keys in regs, reduce across quads)
      float mx = s[0][0];
      for (int nt = 0; nt < 4; nt++)
        for (int r = 0; r < 4; r++) mx = fmaxf(mx, s[nt][r]);
      mx = fmaxf(mx, __shfl_xor(mx, 16, 64));
      mx = fmaxf(mx, __shfl_xor(mx, 32, 64));
      float mn = fmaxf(m_s[g], mx);
      float al = exp2f(m_s[g] - mn);
      float p[4][4], sum = 0.0f;
      for (int nt = 0; nt < 4; nt++)
        for (int r = 0; r < 4; r++) {
          p[nt][r] = exp2f(s[nt][r] - mn);
          sum += p[nt][r];
        }
      sum += __shfl_xor(sum, 16, 64);
      sum += __shfl_xor(sum, 32, 64);
      l_s[g] = l_s[g] * al + sum;
      m_s[g] = mn;

      // packed P writes: P[query=lr][key=16nt+4quad+r]
      for (int nt = 0; nt < 4; nt++) {
        bf16x4 pk;
        for (int r = 0; r < 4; r++) pk[r] = (bf16)p[nt][r];
        *(bf16x4*)&Ps[lr * 64 + ((2 * nt + (quad >> 1)) ^ (lr & 7)) * 8 +
                      (quad & 1) * 4] = pk;
      }

      // rescale O accumulator (rows = query = quad*4+r); al gathered in-wave
      for (int r = 0; r < 4; r++) {
        float a = __shfl(al, quad * 4 + r, 16);
        for (int in = 0; in < 4; in++) oacc[g][in][r] *= a;
      }

      bf16x8 aP[2];
      for (int kk = 0; kk < 2; kk++)
        aP[kk] = *(const bf16x8*)&Ps[lr * 64 + ((4 * kk + quad) ^ (lr & 7)) * 8];
      for (int kk = 0; kk < 2; kk++)
        for (int in = 0; in < 4; in++)
          oacc[g][in] = __builtin_amdgcn_mfma_f32_16x16x32_bf16(
              aP[kk], bv[kk][in], oacc[g][in], 0, 0, 0);
    }
    // stage issued at tile start has landed (whole compute passed): free wait
    asm volatile("s_waitcnt vmcnt(0)" ::: "memory");
    __builtin_amdgcn_s_barrier();
  }

  // epilogue: normalized bf16 partials + lse
  bf16* ob = opb + (size_t)sp * SPLIT_ELEMS;
  size_t rbase = (size_t)(b * HEADS + h) * N2;
  for (int g = 0; g < 2; g++) {
    for (int r = 0; r < 4; r++) {
      float lrow = __shfl(l_s[g], quad * 4 + r, 16);
      float inv = 1.0f / lrow;
      int qq = wv * 32 + g * 16 + quad * 4 + r;
      for (int in = 0; in < 4; in++)
        ob[(rbase + qq) * 64 + in * 16 + lr] = (bf16)(oacc[g][in][r] * inv);
    }
    if (quad == 0) {
      int qq = wv * 32 + g * 16 + lr;
      lseb[(size_t)sp * ROWS_TOTAL + rbase + qq] = m_s[g] + __log2f(l_s[g]);
    }
  }
}

// ---------------------------------------------------------------------------
// Combine (unchanged)
// ---------------------------------------------------------------------------
__global__ __launch_bounds__(256) void combine_kernel(const bf16* __restrict__ opb,
                                                      const float* __restrict__ lseb,
                                                      bf16* __restrict__ out) {
  int gid = blockIdx.x * 256 + threadIdx.x;
  int d = gid & 63;
  int rq = gid >> 6;  // (b*16+h)*256 + q
  int qq = rq & 255, bh = rq >> 8;
  int h = bh & 15, b = bh >> 4;
  float ls[ASPLIT];
  for (int s = 0; s < ASPLIT; s++) ls[s] = lseb[(size_t)s * ROWS_TOTAL + rq];
  float M = fmaxf(fmaxf(ls[0], ls[1]), fmaxf(ls[2], ls[3]));
  float L = 0.0f, o = 0.0f;
  for (int s = 0; s < ASPLIT; s++) {
    float w = exp2f(ls[s] - M);
    L += w;
    o += w * (float)opb[(size_t)s * SPLIT_ELEMS + (size_t)rq * 64 + d];
  }
  out[((size_t)(b * N2 + qq)) * INNER + h * DH + d] = (bf16)(o / L);
}

// ---------------------------------------------------------------------------
extern "C" void kernel_launch(void* const* d_in, const int* in_sizes, int n_in,
                              void* d_out, int out_size, void* d_ws,
                              size_t ws_size, hipStream_t stream) {
  const float* x       = (const float*)d_in[0];
  const float* latents = (const float*)d_in[1];
  const float* shift   = (const float*)d_in[2];
  const float* scale   = (const float*)d_in[3];
  const float* ln1w    = (const float*)d_in[4];
  const float* ln1b    = (const float*)d_in[5];
  const float* ln2w    = (const float*)d_in[6];
  const float* ln2b    = (const float*)d_in[7];
  const float* Wq      = (const float*)d_in[8];
  const float* Wkv     = (const float*)d_in[9];
  const float* Wout    = (const float*)d_in[10];

  char* ws = (char*)d_ws;
  bf16*  xn    = (bf16*)(ws);                // 32MiB; dead after gemm_kv
  bf16*  opb   = (bf16*)(ws);                //   overlay: 4 bf16 splits
  bf16*  lnl   = (bf16*)(ws + 33554432);     // 2MB; dead after q gemm
  float* lseb  = (float*)(ws + 33554432);    //   overlay: lse 256KB
  bf16*  qb    = (bf16*)(ws + 35651584);     // 2MB
  bf16*  kb    = (bf16*)(ws + 37748736);     // 32MiB (K half)
  bf16*  vtb   = (bf16*)(ws + 104857600);    // 32MiB (V^T)
  bf16*  aob   = (bf16*)(ws + 138412032);    // 2MB
  bf16*  WqT   = (bf16*)(ws + 140509184);    // 2MB
  bf16*  WkvT  = (bf16*)(ws + 142606336);    // 4MB
  bf16*  WoutT = (bf16*)(ws + 146800640);    // 2MB

  static bool attr_done = false;
  if (!attr_done) {
    hipFuncSetAttribute(reinterpret_cast<const void*>(gemm_kv256),
                        hipFuncAttributeMaxDynamicSharedMemorySize, 131072);
    attr_done = true;
  }

  prep<<<8448, 256, 0, stream>>>(Wq, Wkv, Wout, WqT, WkvT, WoutT, x, latents,
                                 ln1w, ln1b, ln2w, ln2b, xn, lnl);
  gemm_kv256<<<dim3(512), dim3(512), 131072, stream>>>(xn, WkvT, kb, vtb);
  gemm64<1><<<dim3(16, 16), 256, 0, stream>>>(lnl, WqT, qb, 1024, 1024, shift,
                                              scale);
  attn_kernel<<<dim3(ASPLIT, 16, 4), 512, 0, stream>>>(qb, kb, vtb, opb,
                                                       lseb);
  combine_kernel<<<16384, 256, 0, stream>>>(opb, lseb, aob);
  gemm64<2><<<dim3(16, 16), 256, 0, stream>>>(aob, WoutT, d_out, 1024, 1024,
                                              nullptr, nullptr);
}

// Round 5
// 265.693 us; speedup vs baseline: 1.1832x; 1.0236x over previous
//
#include <hip/hip_runtime.h>

typedef __bf16 bf16;
typedef bf16 bf16x8 __attribute__((ext_vector_type(8)));
typedef bf16 bf16x4 __attribute__((ext_vector_type(4)));
typedef float f32x4 __attribute__((ext_vector_type(4)));

#define B_ 4
#define N1 4096
#define N2 256
#define DIM 1024
#define HEADS 16
#define DH 64
#define INNER 1024
#define ASPLIT 4
#define KEYS_PER_SPLIT (N1 / ASPLIT)      // 1024
#define SPLIT_ELEMS (4 * 16 * 256 * 64)   // elems per split partial (bf16)
#define ROWS_TOTAL (4 * HEADS * N2)       // 16384 rows per split

// async global->LDS, 16B per lane; LDS dest = wave-uniform base + lane*16
typedef __attribute__((address_space(1))) const void gvoid_t;
typedef __attribute__((address_space(3))) void lvoid_t;
__device__ __forceinline__ void async16(const void* g, void* l) {
  __builtin_amdgcn_global_load_lds((gvoid_t*)g, (lvoid_t*)l, 16, 0, 0);
}

// ---------------------------------------------------------------------------
// prep: fused weight transposes + both LayerNorms in one launch. (unchanged)
// ---------------------------------------------------------------------------
__global__ __launch_bounds__(256) void prep(
    const float* __restrict__ Wq, const float* __restrict__ Wkv,
    const float* __restrict__ Wout, bf16* __restrict__ WqT,
    bf16* __restrict__ WkvT, bf16* __restrict__ WoutT,
    const float* __restrict__ x, const float* __restrict__ latents,
    const float* __restrict__ ln1w, const float* __restrict__ ln1b,
    const float* __restrict__ ln2w, const float* __restrict__ ln2b,
    bf16* __restrict__ xn, bf16* __restrict__ lnl) {
  __shared__ float tile[32][33];
  int t = blockIdx.x;
  if (t < 4096) {  // ---- transpose path ----
    const float* src;
    bf16* dst;
    int N;
    if (t < 1024) { src = Wq; dst = WqT; N = 1024; }
    else if (t < 3072) { t -= 1024; src = Wkv; dst = WkvT; N = 2048; }
    else { t -= 3072; src = Wout; dst = WoutT; N = 1024; }
    int ntiles = N >> 5;
    int n0 = (t % ntiles) * 32, k0 = (t / ntiles) * 32;
    int xx = threadIdx.x & 31, yy = threadIdx.x >> 5;
    for (int j = 0; j < 4; j++)
      tile[yy + 8 * j][xx] = src[(size_t)(k0 + yy + 8 * j) * N + n0 + xx];
    __syncthreads();
    for (int j = 0; j < 4; j++)
      dst[(size_t)(n0 + yy + 8 * j) * 1024 + k0 + xx] = (bf16)tile[xx][yy + 8 * j];
    return;
  }
  // ---- LN path ----
  int wv = threadIdx.x >> 6, lane = threadIdx.x & 63;
  int grow = (t - 4096) * 4 + wv;
  const float *src, *w, *bb;
  bf16* dst;
  int row;
  if (grow < 16384) { src = x; w = ln1w; bb = ln1b; dst = xn; row = grow; }
  else { src = latents; w = ln2w; bb = ln2b; dst = lnl; row = grow - 16384; }
  const float4* p = (const float4*)(src + (size_t)row * DIM);
  float4 v[4];
  for (int j = 0; j < 4; j++) v[j] = p[j * 64 + lane];
  float s = 0.f, sq = 0.f;
  for (int j = 0; j < 4; j++) {
    s += v[j].x + v[j].y + v[j].z + v[j].w;
    sq += v[j].x * v[j].x + v[j].y * v[j].y + v[j].z * v[j].z + v[j].w * v[j].w;
  }
  for (int off = 32; off; off >>= 1) {
    s += __shfl_xor(s, off, 64);
    sq += __shfl_xor(sq, off, 64);
  }
  float mu = s * (1.0f / DIM);
  float var = sq * (1.0f / DIM) - mu * mu;
  float r = rsqrtf(var + 1e-5f);
  for (int j = 0; j < 4; j++) {
    float4 wv4 = ((const float4*)w)[j * 64 + lane];
    float4 bv4 = ((const float4*)bb)[j * 64 + lane];
    bf16x4 o;
    o[0] = (bf16)((v[j].x - mu) * r * wv4.x + bv4.x);
    o[1] = (bf16)((v[j].y - mu) * r * wv4.y + bv4.y);
    o[2] = (bf16)((v[j].z - mu) * r * wv4.z + bv4.z);
    o[3] = (bf16)((v[j].w - mu) * r * wv4.w + bv4.w);
    *(bf16x4*)(dst + (size_t)row * DIM + (j * 64 + lane) * 4) = o;
  }
}

// ---------------------------------------------------------------------------
// Big GEMM (kv): 256x256 tile, BK=64, 8-phase schedule with counted vmcnt.
// (round-1 version verbatim: 74-76 us verified)
// ---------------------------------------------------------------------------
__device__ __forceinline__ int swz_off(int row, int cb) {
  int line = row >> 1;
  return (line << 7) + (((((row & 1) << 2) | cb) ^ (line & 7)) << 4);
}

__global__ __launch_bounds__(512, 2) void gemm_kv256(
    const bf16* __restrict__ A, const bf16* __restrict__ Bt,
    bf16* __restrict__ Cout, bf16* __restrict__ Cout2) {
  extern __shared__ char smem[];
  int tid = threadIdx.x;
  int lane = tid & 63, wv = tid >> 6;
  int lr = lane & 15, quad = lane >> 4;
  int wr = wv >> 2, wc = wv & 3;
  int bid = blockIdx.x;  // 512 blocks; XCD-bijective remap (512 % 8 == 0)
  int mt = (bid & 7) * 8 + ((bid >> 3) >> 3), nt = (bid >> 3) & 7;
  int m0 = mt * 256, n0 = nt * 256;

  // fragment byte-offsets within a khalf tile
  int offA[8], offB[4];
#pragma unroll
  for (int im = 0; im < 8; im++) offA[im] = swz_off(wr * 128 + im * 16 + lr, quad);
#pragma unroll
  for (int in = 0; in < 4; in++) offB[in] = swz_off(wc * 64 + in * 16 + lr, quad);

  // staging: unit u = s*512+tid holds logical (row, cb) of the khalf tile
  size_t gA[2], gB[2];
#pragma unroll
  for (int s = 0; s < 2; s++) {
    int u = s * 512 + tid;
    int line = u >> 3, inner = (u & 7) ^ (line & 7);
    int row = line * 2 + (inner >> 2), cb = inner & 3;
    gA[s] = (size_t)(m0 + row) * 1024 + cb * 8;
    gB[s] = (size_t)(n0 + row) * 1024 + cb * 8;
  }
  int ldsS0 = wv * 1024, ldsS1 = 8192 + wv * 1024;  // wave-uniform LDS dests

  auto stA = [&](int b, int kh, int k0) {
    char* base = smem + b * 32768 + kh * 16384;
    async16(&A[gA[0] + k0], base + ldsS0);
    async16(&A[gA[1] + k0], base + ldsS1);
  };
  auto stB = [&](int b, int kh, int k0) {
    char* base = smem + 65536 + b * 32768 + kh * 16384;
    async16(&Bt[gB[0] + k0], base + ldsS0);
    async16(&Bt[gB[1] + k0], base + ldsS1);
  };

  f32x4 acc[8][4] = {};

  // prologue: tile0 (kh0,kh1) + tile1 kh0; allow tile1-kh0's 4 loads in flight
  stA(0, 0, 0);  stB(0, 0, 0);
  stA(0, 1, 32); stB(0, 1, 32);
  stA(1, 0, 64); stB(1, 0, 64);
  asm volatile("s_waitcnt vmcnt(4)" ::: "memory");
  __builtin_amdgcn_s_barrier();

#pragma unroll 1
  for (int t = 0; t < 16; t++) {
    int b = t & 1;
    const char* A0 = smem + b * 32768;
    const char* A1 = A0 + 16384;
    const char* B0 = smem + 65536 + b * 32768;
    const char* B1 = B0 + 16384;
    // clamped tails restage identical bytes -> harmless, keeps vmcnt uniform
    int k1 = (t + 1 < 16 ? t + 1 : 15) * 64;
    int k2 = (t + 2 < 16 ? t + 2 : 15) * 64;
    bf16x8 af[4], bfr[4];
    // ---- P1: kh0, mh0 ----
#pragma unroll
    for (int in = 0; in < 4; in++) bfr[in] = *(const bf16x8*)(B0 + offB[in]);
#pragma unroll
    for (int im = 0; im < 4; im++) af[im] = *(const bf16x8*)(A0 + offA[im]);
    stA(b ^ 1, 1, k1 + 32);
    __builtin_amdgcn_s_barrier();
    __builtin_amdgcn_s_setprio(1);
#pragma unroll
    for (int im = 0; im < 4; im++)
#pragma unroll
      for (int in = 0; in < 4; in++)
        acc[im][in] = __builtin_amdgcn_mfma_f32_16x16x32_bf16(
            af[im], bfr[in], acc[im][in], 0, 0, 0);
    __builtin_amdgcn_s_setprio(0);
    __builtin_amdgcn_s_barrier();
    // ---- P2: kh0, mh1 ----
#pragma unroll
    for (int im = 0; im < 4; im++) af[im] = *(const bf16x8*)(A0 + offA[4 + im]);
    stB(b ^ 1, 1, k1 + 32);
    __builtin_amdgcn_s_barrier();
    __builtin_amdgcn_s_setprio(1);
#pragma unroll
    for (int im = 0; im < 4; im++)
#pragma unroll
      for (int in = 0; in < 4; in++)
        acc[4 + im][in] = __builtin_amdgcn_mfma_f32_16x16x32_bf16(
            af[im], bfr[in], acc[4 + im][in], 0, 0, 0);
    __builtin_amdgcn_s_setprio(0);
    __builtin_amdgcn_s_barrier();
    // ---- P3: kh1, mh0 ----
#pragma unroll
    for (int in = 0; in < 4; in++) bfr[in] = *(const bf16x8*)(B1 + offB[in]);
#pragma unroll
    for (int im = 0; im < 4; im++) af[im] = *(const bf16x8*)(A1 + offA[im]);
    stA(b, 0, k2);  // kh0 of this buffer: fully read at P1/P2, freed by P2's barrier
    __builtin_amdgcn_s_barrier();
    __builtin_amdgcn_s_setprio(1);
#pragma unroll
    for (int im = 0; im < 4; im++)
#pragma unroll
      for (int in = 0; in < 4; in++)
        acc[im][in] = __builtin_amdgcn_mfma_f32_16x16x32_bf16(
            af[im], bfr[in], acc[im][in], 0, 0, 0);
    __builtin_amdgcn_s_setprio(0);
    __builtin_amdgcn_s_barrier();
    // ---- P4: kh1, mh1 ----
#pragma unroll
    for (int im = 0; im < 4; im++) af[im] = *(const bf16x8*)(A1 + offA[4 + im]);
    stB(b, 0, k2);
    __builtin_amdgcn_s_barrier();
    __builtin_amdgcn_s_setprio(1);
#pragma unroll
    for (int im = 0; im < 4; im++)
#pragma unroll
      for (int in = 0; in < 4; in++)
        acc[4 + im][in] = __builtin_amdgcn_mfma_f32_16x16x32_bf16(
            af[im], bfr[in], acc[4 + im][in], 0, 0, 0);
    __builtin_amdgcn_s_setprio(0);
    // counted guard BEFORE the tile-end barrier: all but the newest 4 loads
    // (P3+P4 stages) have landed in every wave; barrier publishes cross-wave.
    asm volatile("s_waitcnt vmcnt(4)" ::: "memory");
    __builtin_amdgcn_s_barrier();
  }

  // drain remaining in-flight stages before reusing LDS in the epilogue
  asm volatile("s_waitcnt vmcnt(0)" ::: "memory");
  __builtin_amdgcn_s_barrier();

  if (n0 < 1024) {
    // K half: direct bf16 stores (L2 combines the 16-lane segments)
#pragma unroll
    for (int im = 0; im < 8; im++)
#pragma unroll
      for (int in = 0; in < 4; in++) {
        int col = n0 + wc * 64 + in * 16 + lr;
#pragma unroll
        for (int r = 0; r < 4; r++) {
          int row = m0 + wr * 128 + im * 16 + quad * 4 + r;
          Cout[(size_t)row * 1024 + col] = (bf16)acc[im][in][r];
        }
      }
    return;
  }
  // V half: per-wave LDS transpose (own 8704B region), b128 stores along key
  int b2 = m0 >> 12;
  int key0 = (m0 & 4095) + wr * 128;
  int gc0 = (n0 - 1024) + wc * 64;
  bf16* Tw = (bf16*)(smem + wv * 8704);  // [32 cols][136 keys pitch]
  for (int pass = 0; pass < 2; pass++) {
#pragma unroll
    for (int ii = 0; ii < 2; ii++) {
      int in = pass * 2 + ii;
      int cl = ii * 16 + lr;
#pragma unroll
      for (int im = 0; im < 8; im++) {
        bf16x4 pk;
#pragma unroll
        for (int r = 0; r < 4; r++) pk[r] = (bf16)acc[im][in][r];
        *(bf16x4*)&Tw[cl * 136 + im * 16 + quad * 4] = pk;
      }
    }
    asm volatile("s_waitcnt lgkmcnt(0)" ::: "memory");
#pragma unroll
    for (int j = 0; j < 8; j++) {
      int idx = j * 64 + lane;
      int cl = idx >> 4, k8 = idx & 15;
      uint4 val = *(const uint4*)&Tw[cl * 136 + k8 * 8];
      *(uint4*)&Cout2[((size_t)(b2 * 1024 + gc0 + pass * 32 + cl)) * 4096 +
                      key0 + k8 * 8] = val;
    }
    asm volatile("s_waitcnt lgkmcnt(0)" ::: "memory");
  }
}

// ---------------------------------------------------------------------------
// Small GEMM: 64x64 tile, BK=64, 3-buffer rotation with counted vmcnt.
// (round-3 version, kept)
// ---------------------------------------------------------------------------
template <int MODE>
__global__ __launch_bounds__(256) void gemm64(
    const bf16* __restrict__ A, const bf16* __restrict__ Bt,
    void* __restrict__ Cout, int K, int N,
    const float* __restrict__ shiftp, const float* __restrict__ scalep) {
  __shared__ __align__(16) bf16 As[3][64 * 64];
  __shared__ __align__(16) bf16 Bs[3][64 * 64];
  int tid = threadIdx.x;
  int lane = tid & 63, wv = tid >> 6;
  int wr = wv >> 1, wc = wv & 1;
  int quad = lane >> 4, lr = lane & 15;
  int m0 = blockIdx.y * 64, n0 = blockIdx.x * 64;
  f32x4 acc[2][2] = {};

  auto stage = [&](int step, int buf) {
    int kt = step * 64;
    for (int j = 0; j < 2; j++) {
      int idx0 = j * 256 + wv * 64;
      int row = (idx0 >> 3) + (lane >> 3);
      int cb = (lane & 7) ^ (row & 7);
      async16(&A[(size_t)(m0 + row) * K + kt + cb * 8], &As[buf][idx0 * 8]);
      async16(&Bt[(size_t)(n0 + row) * K + kt + cb * 8], &Bs[buf][idx0 * 8]);
    }
  };

  int nsteps = K >> 6;  // 16
  stage(0, 0);
  stage(1, 1);
  asm volatile("s_waitcnt vmcnt(4)" ::: "memory");
  __builtin_amdgcn_s_barrier();

#pragma unroll 1
  for (int s = 0; s < nsteps; s++) {
    int cur = s % 3;
    int nxt = (s + 2 < nsteps) ? s + 2 : nsteps - 1;  // tail: dead restage
    stage(nxt, (s + 2) % 3);
    for (int kk = 0; kk < 2; kk++) {
      bf16x8 af[2], bfr[2];
      for (int im = 0; im < 2; im++) {
        int row = wr * 32 + im * 16 + lr;
        af[im] =
            *(const bf16x8*)&As[cur][row * 64 + ((quad + 4 * kk) ^ (row & 7)) * 8];
      }
      for (int in = 0; in < 2; in++) {
        int row = wc * 32 + in * 16 + lr;
        bfr[in] =
            *(const bf16x8*)&Bs[cur][row * 64 + ((quad + 4 * kk) ^ (row & 7)) * 8];
      }
      for (int im = 0; im < 2; im++)
        for (int in = 0; in < 2; in++)
          acc[im][in] = __builtin_amdgcn_mfma_f32_16x16x32_bf16(
              af[im], bfr[in], acc[im][in], 0, 0, 0);
    }
    asm volatile("s_waitcnt vmcnt(4)" ::: "memory");
    __builtin_amdgcn_s_barrier();
  }

  for (int im = 0; im < 2; im++)
    for (int in = 0; in < 2; in++) {
      int col = n0 + wc * 32 + in * 16 + lr;
      for (int r = 0; r < 4; r++) {
        int row = m0 + wr * 32 + im * 16 + quad * 4 + r;
        float v = acc[im][in][r];
        if (MODE == 1) {
          int bb = row >> 8, hh = col >> 6;
          float sc = scalep[bb * 16 + hh], sh = shiftp[bb * 16 + hh];
          ((bf16*)Cout)[(size_t)row * N + col] =
              (bf16)((v * (1.0f + sc) + sh) * 0.18033688011112042f);
        } else {
          ((float*)Cout)[(size_t)row * N + col] = v;
        }
      }
    }
}

// ---------------------------------------------------------------------------
// Flash attention: merged q-tiles (round-4 structure) + exact defer-rescale:
// when no lane's running max grows, al == 1.0 exactly -> the O-rescale
// (4 shfl + 32 mults per g per tile) is a provable no-op; skip it.
// Bit-identical output.
// ---------------------------------------------------------------------------
__global__ __launch_bounds__(512) void attn_kernel(const bf16* __restrict__ q,
                                                   const bf16* __restrict__ kb,
                                                   const bf16* __restrict__ vt,
                                                   bf16* __restrict__ opb,
                                                   float* __restrict__ lseb) {
  int b = blockIdx.z, h = blockIdx.y;
  int sp = blockIdx.x;
  int tid = threadIdx.x, lane = tid & 63, wv = tid >> 6;
  int quad = lane >> 4, lr = lane & 15;
  __shared__ __align__(16) bf16 Ks[2][64 * 64];
  __shared__ __align__(16) bf16 Vs[2][64 * 64];   // [dh][key]
  __shared__ __align__(16) bf16 QP[256 * 64];     // 256 Q rows; P overlays own rows

  // stage all 256 Q rows (4 async16/thread, 8 waves x 8 rows per pass)
  const bf16* qg = q + (size_t)(b * N2) * INNER + h * DH;
  for (int j = 0; j < 4; j++) {
    int r0 = j * 64 + wv * 8;
    int r = r0 + (lane >> 3);
    async16(&qg[(size_t)r * INNER + ((lane & 7) ^ (r & 7)) * 8], &QP[r0 * 64]);
  }
  __syncthreads();
  bf16x8 aQ[2][2];
  for (int g = 0; g < 2; g++) {
    int row = wv * 32 + g * 16 + lr;
    for (int kk = 0; kk < 2; kk++)
      aQ[g][kk] = *(const bf16x8*)&QP[row * 64 + ((quad + 4 * kk) ^ (row & 7)) * 8];
  }
  float m_s[2] = {-1e30f, -1e30f}, l_s[2] = {0.0f, 0.0f};
  f32x4 oacc[2][4] = {};

  const bf16* kg = kb + (size_t)(b * N1) * 1024 + h * DH;
  const bf16* vg = vt + (size_t)((b * HEADS + h) * DH) * N1;
  bf16* Ps = QP + wv * 2048;  // wave's own 32 Q rows (Q already in regs)

  auto stageKV = [&](int t, int buf) {
    int key0 = sp * KEYS_PER_SPLIT + t * 64;
    int r0 = wv * 8;                 // 8 waves x 8 rows = 64 rows in one pass
    int r = r0 + (lane >> 3);
    int cs = ((lane & 7) ^ (r & 7)) * 8;
    async16(&kg[(size_t)(key0 + r) * 1024 + cs], &Ks[buf][r0 * 64]);
    async16(&vg[(size_t)r * N1 + key0 + cs], &Vs[buf][r0 * 64]);
  };

  // prologue: tile 0 into buf 0
  stageKV(0, 0);
  asm volatile("s_waitcnt vmcnt(0)" ::: "memory");
  __builtin_amdgcn_s_barrier();

  for (int t = 0; t < KEYS_PER_SPLIT / 64; t++) {
    int cur = t & 1;
    // hoist K/V fragments once, reuse across both q-groups
    bf16x8 ak[2][4], bv[2][4];
    for (int kk = 0; kk < 2; kk++)
      for (int nt = 0; nt < 4; nt++) {
        int row = nt * 16 + lr;
        ak[kk][nt] =
            *(const bf16x8*)&Ks[cur][row * 64 + ((quad + 4 * kk) ^ (row & 7)) * 8];
        bv[kk][nt] =
            *(const bf16x8*)&Vs[cur][row * 64 + ((quad + 4 * kk) ^ (row & 7)) * 8];
      }
    if (t + 1 < KEYS_PER_SPLIT / 64) stageKV(t + 1, cur ^ 1);

    for (int g = 0; g < 2; g++) {
      f32x4 s[4] = {};
      for (int kk = 0; kk < 2; kk++)
        for (int nt = 0; nt < 4; nt++)
          s[nt] = __builtin_amdgcn_mfma_f32_16x16x32_bf16(ak[kk][nt], aQ[g][kk],
                                                          s[nt], 0, 0, 0);
      // per-lane softmax for query = lr (16 keys in regs, reduce across quads)
      float mx = s[0][0];
      for (int nt = 0; nt < 4; nt++)
        for (int r = 0; r < 4; r++) mx = fmaxf(mx, s[nt][r]);
      mx = fmaxf(mx, __shfl_xor(mx, 16, 64));
      mx = fmaxf(mx, __shfl_xor(mx, 32, 64));
      float mo = m_s[g];
      float mn = fmaxf(mo, mx);
      float al = exp2f(mo - mn);
      float p[4][4], sum = 0.0f;
      for (int nt = 0; nt < 4; nt++)
        for (int r = 0; r < 4; r++) {
          p[nt][r] = exp2f(s[nt][r] - mn);
          sum += p[nt][r];
        }
      sum += __shfl_xor(sum, 16, 64);
      sum += __shfl_xor(sum, 32, 64);
      l_s[g] = l_s[g] * al + sum;
      m_s[g] = mn;

      // packed P writes: P[query=lr][key=16nt+4quad+r]
      for (int nt = 0; nt < 4; nt++) {
        bf16x4 pk;
        for (int r = 0; r < 4; r++) pk[r] = (bf16)p[nt][r];
        *(bf16x4*)&Ps[lr * 64 + ((2 * nt + (quad >> 1)) ^ (lr & 7)) * 8 +
                      (quad & 1) * 4] = pk;
      }

      // rescale O accumulator only when some lane's max grew (al != 1.0);
      // otherwise al == 1.0 exactly and the rescale is a no-op.
      if (__any(mn > mo)) {
        for (int r = 0; r < 4; r++) {
          float a = __shfl(al, quad * 4 + r, 16);
          for (int in = 0; in < 4; in++) oacc[g][in][r] *= a;
        }
      }

      bf16x8 aP[2];
      for (int kk = 0; kk < 2; kk++)
        aP[kk] = *(const bf16x8*)&Ps[lr * 64 + ((4 * kk + quad) ^ (lr & 7)) * 8];
      for (int kk = 0; kk < 2; kk++)
        for (int in = 0; in < 4; in++)
          oacc[g][in] = __builtin_amdgcn_mfma_f32_16x16x32_bf16(
              aP[kk], bv[kk][in], oacc[g][in], 0, 0, 0);
    }
    // stage issued at tile start has landed (whole compute passed): free wait
    asm volatile("s_waitcnt vmcnt(0)" ::: "memory");
    __builtin_amdgcn_s_barrier();
  }

  // epilogue: normalized bf16 partials + lse
  bf16* ob = opb + (size_t)sp * SPLIT_ELEMS;
  size_t rbase = (size_t)(b * HEADS + h) * N2;
  for (int g = 0; g < 2; g++) {
    for (int r = 0; r < 4; r++) {
      float lrow = __shfl(l_s[g], quad * 4 + r, 16);
      float inv = 1.0f / lrow;
      int qq = wv * 32 + g * 16 + quad * 4 + r;
      for (int in = 0; in < 4; in++)
        ob[(rbase + qq) * 64 + in * 16 + lr] = (bf16)(oacc[g][in][r] * inv);
    }
    if (quad == 0) {
      int qq = wv * 32 + g * 16 + lr;
      lseb[(size_t)sp * ROWS_TOTAL + rbase + qq] = m_s[g] + __log2f(l_s[g]);
    }
  }
}

// ---------------------------------------------------------------------------
// Combine: out = sum_s W_s O_s / sum_s W_s, W_s = 2^(lse_s - max lse).
// FIXED: grid was 16384 blocks (4x too many threads -> OOB reads of lseb/opb
// and OOB writes past d_out). Now one thread per 8-elem d-chunk: 512 blocks,
// bf16x8 vector loads/stores (16B/lane).
// ---------------------------------------------------------------------------
__global__ __launch_bounds__(256) void combine_kernel(const bf16* __restrict__ opb,
                                                      const float* __restrict__ lseb,
                                                      bf16* __restrict__ out) {
  int gid = blockIdx.x * 256 + threadIdx.x;  // 131072 threads total
  int dc = (gid & 7) * 8;
  int rq = gid >> 3;  // (b*16+h)*256 + q, in [0, 16384)
  int qq = rq & 255, bh = rq >> 8;
  int h = bh & 15, b = bh >> 4;
  float ls[ASPLIT];
  for (int s = 0; s < ASPLIT; s++) ls[s] = lseb[(size_t)s * ROWS_TOTAL + rq];
  float M = fmaxf(fmaxf(ls[0], ls[1]), fmaxf(ls[2], ls[3]));
  float L = 0.0f, w[ASPLIT];
  for (int s = 0; s < ASPLIT; s++) {
    w[s] = exp2f(ls[s] - M);
    L += w[s];
  }
  float inv = 1.0f / L;
  float o[8] = {};
  for (int s = 0; s < ASPLIT; s++) {
    bf16x8 v = *(const bf16x8*)&opb[(size_t)s * SPLIT_ELEMS + (size_t)rq * 64 + dc];
    for (int j = 0; j < 8; j++) o[j] += w[s] * (float)v[j];
  }
  bf16x8 ov;
  for (int j = 0; j < 8; j++) ov[j] = (bf16)(o[j] * inv);
  *(bf16x8*)&out[((size_t)(b * N2 + qq)) * INNER + h * DH + dc] = ov;
}

// ---------------------------------------------------------------------------
extern "C" void kernel_launch(void* const* d_in, const int* in_sizes, int n_in,
                              void* d_out, int out_size, void* d_ws,
                              size_t ws_size, hipStream_t stream) {
  const float* x       = (const float*)d_in[0];
  const float* latents = (const float*)d_in[1];
  const float* shift   = (const float*)d_in[2];
  const float* scale   = (const float*)d_in[3];
  const float* ln1w    = (const float*)d_in[4];
  const float* ln1b    = (const float*)d_in[5];
  const float* ln2w    = (const float*)d_in[6];
  const float* ln2b    = (const float*)d_in[7];
  const float* Wq      = (const float*)d_in[8];
  const float* Wkv     = (const float*)d_in[9];
  const float* Wout    = (const float*)d_in[10];

  char* ws = (char*)d_ws;
  bf16*  xn    = (bf16*)(ws);                // 32MiB; dead after gemm_kv
  bf16*  opb   = (bf16*)(ws);                //   overlay: 4 bf16 splits
  bf16*  lnl   = (bf16*)(ws + 33554432);     // 2MB; dead after q gemm
  float* lseb  = (float*)(ws + 33554432);    //   overlay: lse 256KB
  bf16*  qb    = (bf16*)(ws + 35651584);     // 2MB
  bf16*  kb    = (bf16*)(ws + 37748736);     // 32MiB (K half)
  bf16*  vtb   = (bf16*)(ws + 104857600);    // 32MiB (V^T)
  bf16*  aob   = (bf16*)(ws + 138412032);    // 2MB
  bf16*  WqT   = (bf16*)(ws + 140509184);    // 2MB
  bf16*  WkvT  = (bf16*)(ws + 142606336);    // 4MB
  bf16*  WoutT = (bf16*)(ws + 146800640);    // 2MB

  static bool attr_done = false;
  if (!attr_done) {
    hipFuncSetAttribute(reinterpret_cast<const void*>(gemm_kv256),
                        hipFuncAttributeMaxDynamicSharedMemorySize, 131072);
    attr_done = true;
  }

  prep<<<8448, 256, 0, stream>>>(Wq, Wkv, Wout, WqT, WkvT, WoutT, x, latents,
                                 ln1w, ln1b, ln2w, ln2b, xn, lnl);
  gemm_kv256<<<dim3(512), dim3(512), 131072, stream>>>(xn, WkvT, kb, vtb);
  gemm64<1><<<dim3(16, 16), 256, 0, stream>>>(lnl, WqT, qb, 1024, 1024, shift,
                                              scale);
  attn_kernel<<<dim3(ASPLIT, 16, 4), 512, 0, stream>>>(qb, kb, vtb, opb,
                                                       lseb);
  combine_kernel<<<512, 256, 0, stream>>>(opb, lseb, aob);
  gemm64<2><<<dim3(16, 16), 256, 0, stream>>>(aob, WoutT, d_out, 1024, 1024,
                                              nullptr, nullptr);
}